// Round 4
// baseline (1674.562 us; speedup 1.0000x reference)
//
#include <hip/hip_runtime.h>
#include <math.h>

#define N_RN 100000
#define N_ED 1200000
#define N_G  4096
#define SCAN_CH 256
#define SCAN_NB ((N_RN + SCAN_CH - 1) / SCAN_CH)   // 391

__device__ __forceinline__ float lrelu(float x) { return x > 0.f ? x : 0.1f * x; }

// h = r_node @ W_r (wave/node, lane=col, row via coalesced LDS); fused hs/hd layer0
__global__ void k_embed_h(const float* __restrict__ r_node,
                          const float* __restrict__ W_r,
                          const float* __restrict__ a_s0,
                          const float* __restrict__ a_d0,
                          float* __restrict__ h,
                          float* __restrict__ hs, float* __restrict__ hd) {
    __shared__ float Wl[64 * 64];
    __shared__ float arow[4][64];
    int tid = threadIdx.x;
    for (int i = tid; i < 4096; i += 256) Wl[i] = W_r[i];
    __syncthreads();
    int lane = tid & 63, w = tid >> 6;
    float asj = a_s0[lane], adj = a_d0[lane];
    int wid = blockIdx.x * 4 + w;
    int nw = gridDim.x * 4;
    for (int n = wid; n < N_RN; n += nw) {
        arow[w][lane] = r_node[(size_t)n * 64 + lane];
        float acc = 0.f;
#pragma unroll
        for (int d4 = 0; d4 < 16; ++d4) {
            float4 a = *(const float4*)&arow[w][d4 * 4];
            int d = d4 * 4;
            acc += a.x * Wl[(d + 0) * 64 + lane];
            acc += a.y * Wl[(d + 1) * 64 + lane];
            acc += a.z * Wl[(d + 2) * 64 + lane];
            acc += a.w * Wl[(d + 3) * 64 + lane];
        }
        h[(size_t)n * 64 + lane] = acc;
        float x = acc * asj, y = acc * adj;
#pragma unroll
        for (int off = 32; off; off >>= 1) {
            x += __shfl_xor(x, off, 64);
            y += __shfl_xor(y, off, 64);
        }
        if (lane == 0) { hs[n] = x; hd[n] = y; }
    }
}

// WeWm[l] = W_e @ Wm[l]  (16x64 per layer); also was_all[l][t] = W_e[t,:] . a_e[l]
__global__ void k_wewm(const float* __restrict__ W_e,
                       const float* __restrict__ Wm,
                       const float* __restrict__ a_e,
                       float* __restrict__ WeWm,
                       float* __restrict__ was_all) {
    int idx = blockIdx.x * blockDim.x + threadIdx.x;   // 17*256
    if (idx < 4096) {
        int l = idx >> 10, rem = idx & 1023;
        int t = rem >> 6, j = rem & 63;
        float acc = 0.f;
        for (int d = 0; d < 64; ++d)
            acc += W_e[t * 64 + d] * Wm[l * 4096 + d * 64 + j];
        WeWm[idx] = acc;
    } else {
        int r = idx - 4096;
        if (r < 64) {
            int l = r >> 4, t = r & 15;
            float acc = 0.f;
            for (int j = 0; j < 64; ++j)
                acc += W_e[t * 64 + j] * a_e[l * 64 + j];
            was_all[r] = acc;
        }
    }
}

// ---- CSR build ----
__global__ void k_hist(const int* __restrict__ dst, int* __restrict__ deg) {
    int k = blockIdx.x * blockDim.x + threadIdx.x;
    if (k < N_ED) atomicAdd(deg + dst[k], 1);
}

__global__ void k_scan_a(const int* __restrict__ deg, int* __restrict__ bsum) {
    __shared__ int lds[SCAN_CH];
    int b = blockIdx.x, t = threadIdx.x;
    int i = b * SCAN_CH + t;
    int v = (i < N_RN) ? deg[i] : 0;
    lds[t] = v;
    __syncthreads();
    for (int d = 128; d; d >>= 1) {
        if (t < d) lds[t] += lds[t + d];
        __syncthreads();
    }
    if (t == 0) bsum[b] = lds[0];
}

__global__ void k_scan_b(int* __restrict__ bsum) {
    __shared__ int lds[512];
    int t = threadIdx.x;
    int v = (t < SCAN_NB) ? bsum[t] : 0;
    lds[t] = v;
    __syncthreads();
    for (int d = 1; d < 512; d <<= 1) {
        int u = (t >= d) ? lds[t - d] : 0;
        __syncthreads();
        lds[t] += u;
        __syncthreads();
    }
    if (t < SCAN_NB) bsum[t] = lds[t] - v;  // exclusive
}

__global__ void k_scan_c(const int* __restrict__ deg, const int* __restrict__ bsum,
                         int* __restrict__ off, int* __restrict__ cur) {
    __shared__ int lds[SCAN_CH];
    int b = blockIdx.x, t = threadIdx.x;
    int i = b * SCAN_CH + t;
    int v = (i < N_RN) ? deg[i] : 0;
    lds[t] = v;
    __syncthreads();
    for (int d = 1; d < SCAN_CH; d <<= 1) {
        int u = (t >= d) ? lds[t - d] : 0;
        __syncthreads();
        lds[t] += u;
        __syncthreads();
    }
    if (i < N_RN) {
        int incl = bsum[b] + lds[t];
        off[i + 1] = incl;
        cur[i] = incl - v;
        if (i == 0) off[0] = 0;
    }
}

// inverted scatter step 1: only a 4B index is scattered
__global__ void k_scatter_idx(const int* __restrict__ dst,
                              int* __restrict__ cur,
                              int* __restrict__ eperm) {
    int k = blockIdx.x * blockDim.x + threadIdx.x;
    if (k >= N_ED) return;
    int pos = atomicAdd(cur + dst[k], 1);
    eperm[pos] = k;
}

// inverted scatter step 2: coalesced writes, gathered reads (L3-absorbed)
__global__ void k_permute(const int* __restrict__ eperm,
                          const int* __restrict__ src,
                          const float* __restrict__ r_edge,
                          int* __restrict__ src_perm,
                          float* __restrict__ r16_perm) {
    int pos = blockIdx.x * blockDim.x + threadIdx.x;
    if (pos >= N_ED) return;
    int k = eperm[pos];
    src_perm[pos] = src[k];
    const float4* row = (const float4*)(r_edge + (size_t)k * 16);
    float4 r0 = row[0], r1 = row[1], r2 = row[2], r3 = row[3];
    float4* o = (float4*)(r16_perm + (size_t)pos * 16);
    o[0] = r0; o[1] = r1; o[2] = r2; o[3] = r3;
}

// fused per-layer conv: 4 nodes per wave (16-lane group per node).
// Work-stealing ticket loop (static first group) flattens the 3-vs-4 iteration tail.
// Phase 2 unrolled x4 for memory-level parallelism.
__global__ void k_layer(const float* __restrict__ h_in,
                        const float* __restrict__ hs, const float* __restrict__ hd,
                        const int* __restrict__ off,
                        const int* __restrict__ src_perm,
                        const float* __restrict__ r16_perm,
                        const float* __restrict__ was_l,   // 16 floats: W_e @ a_e[l]
                        const float* __restrict__ Wm_l,
                        const float* __restrict__ WeWm_l,
                        const float* __restrict__ a_s_n, const float* __restrict__ a_d_n,
                        int* __restrict__ ctr,
                        float* __restrict__ h_out,
                        float* __restrict__ hs_out, float* __restrict__ hd_out) {
    __shared__ float Wl[4096];
    __shared__ float Ww[1024];
    __shared__ float arow[8][4 * 68 + 4];   // 68-pad: groups land on distinct banks
    int tid = threadIdx.x;
    for (int i = tid; i < 4096; i += 512) Wl[i] = Wm_l[i];
    for (int i = tid; i < 1024; i += 512) Ww[i] = WeWm_l[i];
    __syncthreads();
    int lane = tid & 63, w = tid >> 6;
    int g = lane >> 4, lg = lane & 15;
    float wr[16];
#pragma unroll
    for (int t = 0; t < 16; ++t) wr[t] = was_l[t];
    float4 as4 = *(const float4*)&a_s_n[lg << 2];
    float4 ad4 = *(const float4*)&a_d_n[lg << 2];
    int Wv = blockIdx.x * 8 + w;
    int NW = gridDim.x * 8;
    int it = Wv;                       // static first assignment (no atomic burst)
    while (it * 4 < N_RN) {
        int n = it * 4 + g;
        bool nact = n < N_RN;
        int base = 0, end = 0;
        if (nact) { base = off[n]; end = off[n + 1]; }
        float hdn = nact ? hd[n] : 0.f;
        float m = -1e38f, s = 0.f, racc = 0.f;
        float ax = 0.f, ay = 0.f, az = 0.f, aw = 0.f;
        int nch = (end - base + 15) >> 4;
        int nmax = nch;
        nmax = max(nmax, __shfl_xor(nmax, 16, 64));
        nmax = max(nmax, __shfl_xor(nmax, 32, 64));
        for (int c = 0; c < nmax; ++c) {
            int cb = base + (c << 4);
            int rem = end - cb;
            int cnt = rem > 16 ? 16 : (rem > 0 ? rem : 0);
            float lgt = -1e38f;
            float wvv = 0.f;
            int sk = 0;
            bool act = lg < cnt;
            if (act) {
                int pos = cb + lg;
                sk = src_perm[pos];
                const float4* rp = (const float4*)(r16_perm + (size_t)pos * 16);
                float4 r0 = rp[0], r1 = rp[1], r2 = rp[2], r3 = rp[3];
                float ep = r0.x * wr[0] + r0.y * wr[1] + r0.z * wr[2] + r0.w * wr[3]
                         + r1.x * wr[4] + r1.y * wr[5] + r1.z * wr[6] + r1.w * wr[7]
                         + r2.x * wr[8] + r2.y * wr[9] + r2.z * wr[10] + r2.w * wr[11]
                         + r3.x * wr[12] + r3.y * wr[13] + r3.z * wr[14] + r3.w * wr[15];
                lgt = lrelu(hs[sk] + hdn + ep);
            }
            float cm = lgt;
            cm = fmaxf(cm, __shfl_xor(cm, 1, 16));
            cm = fmaxf(cm, __shfl_xor(cm, 2, 16));
            cm = fmaxf(cm, __shfl_xor(cm, 4, 16));
            cm = fmaxf(cm, __shfl_xor(cm, 8, 16));
            float newm = fmaxf(m, cm);
            float scale = (m > -1e37f) ? __expf(m - newm) : 0.f;
            s *= scale; racc *= scale;
            ax *= scale; ay *= scale; az *= scale; aw *= scale;
            m = newm;
            if (act) wvv = __expf(lgt - m);
            s += wvv;
            // phase 2: unrolled x4; lane lg accumulates dims 4lg..4lg+3
            const float* hb = h_in;
            int e = 0;
            for (; e + 3 < cnt; e += 4) {
                float w0 = __shfl(wvv, e, 16);
                float w1 = __shfl(wvv, e + 1, 16);
                float w2 = __shfl(wvv, e + 2, 16);
                float w3 = __shfl(wvv, e + 3, 16);
                int   s0 = __shfl(sk, e, 16);
                int   s1 = __shfl(sk, e + 1, 16);
                int   s2 = __shfl(sk, e + 2, 16);
                int   s3 = __shfl(sk, e + 3, 16);
                const float4 h0v = *(const float4*)(hb + (size_t)s0 * 64 + (lg << 2));
                const float4 h1v = *(const float4*)(hb + (size_t)s1 * 64 + (lg << 2));
                const float4 h2v = *(const float4*)(hb + (size_t)s2 * 64 + (lg << 2));
                const float4 h3v = *(const float4*)(hb + (size_t)s3 * 64 + (lg << 2));
                float q0 = r16_perm[(size_t)(cb + e) * 16 + lg];
                float q1 = r16_perm[(size_t)(cb + e + 1) * 16 + lg];
                float q2 = r16_perm[(size_t)(cb + e + 2) * 16 + lg];
                float q3 = r16_perm[(size_t)(cb + e + 3) * 16 + lg];
                ax += w0 * h0v.x + w1 * h1v.x + w2 * h2v.x + w3 * h3v.x;
                ay += w0 * h0v.y + w1 * h1v.y + w2 * h2v.y + w3 * h3v.y;
                az += w0 * h0v.z + w1 * h1v.z + w2 * h2v.z + w3 * h3v.z;
                aw += w0 * h0v.w + w1 * h1v.w + w2 * h2v.w + w3 * h3v.w;
                racc += w0 * q0 + w1 * q1 + w2 * q2 + w3 * q3;
            }
            for (; e < cnt; ++e) {
                float w0 = __shfl(wvv, e, 16);
                int   s0 = __shfl(sk, e, 16);
                const float4 h0v = *(const float4*)(hb + (size_t)s0 * 64 + (lg << 2));
                float q0 = r16_perm[(size_t)(cb + e) * 16 + lg];
                ax += w0 * h0v.x; ay += w0 * h0v.y;
                az += w0 * h0v.z; aw += w0 * h0v.w;
                racc += w0 * q0;
            }
        }
        // softmax denominator (group sum)
        s += __shfl_xor(s, 1, 16);
        s += __shfl_xor(s, 2, 16);
        s += __shfl_xor(s, 4, 16);
        s += __shfl_xor(s, 8, 16);
        float inv = (end > base) ? 1.f / s : 0.f;
        // stage normalized agg row for the group matvec
        float* ar = &arow[w][g * 68];
        *(float4*)&ar[lg << 2] = make_float4(ax * inv, ay * inv, az * inv, aw * inv);
        float mx = 0.f, my = 0.f, mz = 0.f, mw = 0.f;
#pragma unroll
        for (int d4 = 0; d4 < 16; ++d4) {
            float4 a = *(const float4*)&ar[d4 << 2];      // LDS broadcast within group
            const float* wl = &Wl[(d4 << 2) * 64 + (lg << 2)];
            float4 w0 = *(const float4*)&wl[0];
            float4 w1 = *(const float4*)&wl[64];
            float4 w2 = *(const float4*)&wl[128];
            float4 w3 = *(const float4*)&wl[192];
            mx += a.x * w0.x + a.y * w1.x + a.z * w2.x + a.w * w3.x;
            my += a.x * w0.y + a.y * w1.y + a.z * w2.y + a.w * w3.y;
            mz += a.x * w0.z + a.y * w1.z + a.z * w2.z + a.w * w3.z;
            mw += a.x * w0.w + a.y * w1.w + a.z * w2.w + a.w * w3.w;
        }
        float rs = racc * inv;
#pragma unroll
        for (int t = 0; t < 16; ++t) {
            float rt = __shfl(rs, t, 16);
            const float4 wt = *(const float4*)&Ww[t * 64 + (lg << 2)];
            mx += rt * wt.x; my += rt * wt.y; mz += rt * wt.z; mw += rt * wt.w;
        }
        if (nact) {
            const float4 hi4 = *(const float4*)(h_in + (size_t)n * 64 + (lg << 2));
            float4 hv;
            hv.x = lrelu(hi4.x + mx); hv.y = lrelu(hi4.y + my);
            hv.z = lrelu(hi4.z + mz); hv.w = lrelu(hi4.w + mw);
            *(float4*)(h_out + (size_t)n * 64 + (lg << 2)) = hv;
            float x = hv.x * as4.x + hv.y * as4.y + hv.z * as4.z + hv.w * as4.w;
            float y = hv.x * ad4.x + hv.y * ad4.y + hv.z * ad4.z + hv.w * ad4.w;
            x += __shfl_xor(x, 1, 16); x += __shfl_xor(x, 2, 16);
            x += __shfl_xor(x, 4, 16); x += __shfl_xor(x, 8, 16);
            y += __shfl_xor(y, 1, 16); y += __shfl_xor(y, 2, 16);
            y += __shfl_xor(y, 4, 16); y += __shfl_xor(y, 8, 16);
            if (lg == 0) { hs_out[n] = x; hd_out[n] = y; }
        }
        // steal next group
        int itn = 0;
        if (lane == 0) itn = atomicAdd(ctr, 1);
        it = NW + __shfl(itn, 0, 64);
    }
}

// block per graph readout (graph_id sorted -> contiguous ranges via binary search)
__global__ void k_readout(const float* __restrict__ h,
                          const float* __restrict__ d_edge,
                          const int* __restrict__ graph_id,
                          const float* __restrict__ i_node,
                          const float* __restrict__ W_i,
                          const float* __restrict__ w_d,
                          const float* __restrict__ b_d,
                          const float* __restrict__ W_mlp,
                          const float* __restrict__ b_mlp,
                          const float* __restrict__ W_out,
                          const float* __restrict__ b_out,
                          float* __restrict__ out) {
    int g = blockIdx.x, j = threadIdx.x;
    int lo = 0, hi = N_RN;
    while (lo < hi) { int mid = (lo + hi) >> 1; if (graph_id[mid] < g) lo = mid + 1; else hi = mid; }
    int start = lo;
    hi = N_RN;
    while (lo < hi) { int mid = (lo + hi) >> 1; if (graph_id[mid] < g + 1) lo = mid + 1; else hi = mid; }
    int end = lo;

    float wd = w_d[0], bd = b_d[0];
    float acc0 = 0.f, acc1 = 0.f, sg = 0.f;
    for (int n = start; n < end; ++n) {
        float hv = h[(size_t)n * 64 + j];
        float de = d_edge[n];
        float gate = 1.f / (1.f + __expf(-(de * wd + bd)));
        acc0 += hv;
        acc1 += gate * hv;
        sg += gate;
    }
    float hij = i_node[g] * W_i[j] + acc1;
    float pooled = acc0 + sg * hij;

    __shared__ float xa[64], xb[64];
    xa[j] = pooled;
    __syncthreads();
#pragma unroll
    for (int layer = 0; layer < 3; ++layer) {
        const float* W = W_mlp + layer * 4096;
        float* srcb = (layer & 1) ? xb : xa;
        float* dstb = (layer & 1) ? xa : xb;
        float acc = b_mlp[layer * 64 + j];
        for (int d = 0; d < 64; ++d) acc += srcb[d] * W[d * 64 + j];
        acc = fmaxf(acc, 0.f);
        __syncthreads();
        dstb[j] = acc;
        __syncthreads();
    }
    float v = xb[j] * W_out[j];
#pragma unroll
    for (int off = 32; off; off >>= 1) v += __shfl_xor(v, off, 64);
    if (j == 0) out[g] = v + b_out[0];
}

extern "C" void kernel_launch(void* const* d_in, const int* in_sizes, int n_in,
                              void* d_out, int out_size, void* d_ws, size_t ws_size,
                              hipStream_t stream) {
    const float* r_node  = (const float*)d_in[0];
    const float* i_node  = (const float*)d_in[1];
    const float* r_edge  = (const float*)d_in[2];
    const float* d_edge  = (const float*)d_in[3];
    const int*   r2r_src = (const int*)d_in[4];
    const int*   r2r_dst = (const int*)d_in[5];
    const int*   graph_id= (const int*)d_in[6];
    const float* W_r     = (const float*)d_in[7];
    const float* W_i     = (const float*)d_in[8];
    const float* W_e     = (const float*)d_in[9];
    const float* Wm      = (const float*)d_in[10];
    const float* a_s     = (const float*)d_in[11];
    const float* a_d     = (const float*)d_in[12];
    const float* a_e     = (const float*)d_in[13];
    const float* w_d     = (const float*)d_in[14];
    const float* b_d     = (const float*)d_in[15];
    const float* W_mlp   = (const float*)d_in[16];
    const float* b_mlp   = (const float*)d_in[17];
    const float* W_out   = (const float*)d_in[18];
    const float* b_out   = (const float*)d_in[19];
    float* out = (float*)d_out;

    float* ws = (float*)d_ws;
    float* h0   = ws;                                  // N*64
    float* h1   = h0 + (size_t)N_RN * 64;              // N*64
    float* hs0  = h1 + (size_t)N_RN * 64;              // N
    float* hd0  = hs0 + N_RN;                          // N
    float* hs1  = hd0 + N_RN;                          // N
    float* hd1  = hs1 + N_RN;                          // N
    float* WeWm = hd1 + N_RN;                          // 4*16*64
    float* wasb = WeWm + 4096;                         // 4*16
    int*   deg  = (int*)(wasb + 64);                   // N
    int*   offs = deg + N_RN;                          // N+1
    int*   cur  = offs + N_RN + 1;                     // N
    int*   bsum = cur + N_RN;                          // 512
    int*   ctr  = bsum + 512;                          // 4 (per-layer tickets)
    int*   eperm= ctr + 4;                             // E
    int*   src_perm = eperm + N_ED;                    // E
    float* r16_perm = (float*)(src_perm + N_ED);       // 16*E

    k_embed_h<<<2048, 256, 0, stream>>>(r_node, W_r, a_s, a_d, h0, hs0, hd0);
    k_wewm<<<17, 256, 0, stream>>>(W_e, Wm, a_e, WeWm, wasb);

    hipMemsetAsync(deg, 0, N_RN * sizeof(int), stream);
    hipMemsetAsync(ctr, 0, 4 * sizeof(int), stream);
    k_hist<<<(N_ED + 255) / 256, 256, 0, stream>>>(r2r_dst, deg);
    k_scan_a<<<SCAN_NB, SCAN_CH, 0, stream>>>(deg, bsum);
    k_scan_b<<<1, 512, 0, stream>>>(bsum);
    k_scan_c<<<SCAN_NB, SCAN_CH, 0, stream>>>(deg, bsum, offs, cur);
    k_scatter_idx<<<(N_ED + 255) / 256, 256, 0, stream>>>(r2r_dst, cur, eperm);
    k_permute<<<(N_ED + 255) / 256, 256, 0, stream>>>(eperm, r2r_src, r_edge,
                                                      src_perm, r16_perm);

    float* hin = h0;  float* hout = h1;
    float* hsi = hs0; float* hdi = hd0;
    float* hso = hs1; float* hdo = hd1;
    for (int l = 0; l < 4; ++l) {
        int ln = (l + 1) & 3;
        k_layer<<<1024, 512, 0, stream>>>(hin, hsi, hdi, offs, src_perm, r16_perm,
                                          wasb + l * 16, Wm + l * 4096, WeWm + l * 1024,
                                          a_s + ln * 64, a_d + ln * 64, ctr + l,
                                          hout, hso, hdo);
        float* t;
        t = hin; hin = hout; hout = t;
        t = hsi; hsi = hso; hso = t;
        t = hdi; hdi = hdo; hdo = t;
    }

    k_readout<<<N_G, 64, 0, stream>>>(hin, d_edge, graph_id, i_node, W_i, w_d, b_d,
                                      W_mlp, b_mlp, W_out, b_out, out);
}

// Round 5
// 816.936 us; speedup vs baseline: 2.0498x; 2.0498x over previous
//
#include <hip/hip_runtime.h>
#include <math.h>

#define N_RN 100000
#define N_ED 1200000
#define N_G  4096
#define SCAN_CH 256
#define SCAN_NB ((N_RN + SCAN_CH - 1) / SCAN_CH)   // 391
#define NWAVES 8192                                 // 1024 blocks x 8 waves

__device__ __forceinline__ float lrelu(float x) { return x > 0.f ? x : 0.1f * x; }

// h = r_node @ W_r (wave/node, lane=col, row via coalesced LDS); fused hs/hd layer0
__global__ void k_embed_h(const float* __restrict__ r_node,
                          const float* __restrict__ W_r,
                          const float* __restrict__ a_s0,
                          const float* __restrict__ a_d0,
                          float* __restrict__ h,
                          float* __restrict__ hs, float* __restrict__ hd) {
    __shared__ float Wl[64 * 64];
    __shared__ float arow[4][64];
    int tid = threadIdx.x;
    for (int i = tid; i < 4096; i += 256) Wl[i] = W_r[i];
    __syncthreads();
    int lane = tid & 63, w = tid >> 6;
    float asj = a_s0[lane], adj = a_d0[lane];
    int wid = blockIdx.x * 4 + w;
    int nw = gridDim.x * 4;
    for (int n = wid; n < N_RN; n += nw) {
        arow[w][lane] = r_node[(size_t)n * 64 + lane];
        float acc = 0.f;
#pragma unroll
        for (int d4 = 0; d4 < 16; ++d4) {
            float4 a = *(const float4*)&arow[w][d4 * 4];
            int d = d4 * 4;
            acc += a.x * Wl[(d + 0) * 64 + lane];
            acc += a.y * Wl[(d + 1) * 64 + lane];
            acc += a.z * Wl[(d + 2) * 64 + lane];
            acc += a.w * Wl[(d + 3) * 64 + lane];
        }
        h[(size_t)n * 64 + lane] = acc;
        float x = acc * asj, y = acc * adj;
#pragma unroll
        for (int off = 32; off; off >>= 1) {
            x += __shfl_xor(x, off, 64);
            y += __shfl_xor(y, off, 64);
        }
        if (lane == 0) { hs[n] = x; hd[n] = y; }
    }
}

// WeWm[l] = W_e @ Wm[l]  (16x64 per layer); also was_all[l][t] = W_e[t,:] . a_e[l]
__global__ void k_wewm(const float* __restrict__ W_e,
                       const float* __restrict__ Wm,
                       const float* __restrict__ a_e,
                       float* __restrict__ WeWm,
                       float* __restrict__ was_all) {
    int idx = blockIdx.x * blockDim.x + threadIdx.x;   // 17*256
    if (idx < 4096) {
        int l = idx >> 10, rem = idx & 1023;
        int t = rem >> 6, j = rem & 63;
        float acc = 0.f;
        for (int d = 0; d < 64; ++d)
            acc += W_e[t * 64 + d] * Wm[l * 4096 + d * 64 + j];
        WeWm[idx] = acc;
    } else {
        int r = idx - 4096;
        if (r < 64) {
            int l = r >> 4, t = r & 15;
            float acc = 0.f;
            for (int j = 0; j < 64; ++j)
                acc += W_e[t * 64 + j] * a_e[l * 64 + j];
            was_all[r] = acc;
        }
    }
}

// ---- CSR build ----
__global__ void k_hist(const int* __restrict__ dst, int* __restrict__ deg) {
    int k = blockIdx.x * blockDim.x + threadIdx.x;
    if (k < N_ED) atomicAdd(deg + dst[k], 1);
}

__global__ void k_scan_a(const int* __restrict__ deg, int* __restrict__ bsum) {
    __shared__ int lds[SCAN_CH];
    int b = blockIdx.x, t = threadIdx.x;
    int i = b * SCAN_CH + t;
    int v = (i < N_RN) ? deg[i] : 0;
    lds[t] = v;
    __syncthreads();
    for (int d = 128; d; d >>= 1) {
        if (t < d) lds[t] += lds[t + d];
        __syncthreads();
    }
    if (t == 0) bsum[b] = lds[0];
}

__global__ void k_scan_b(int* __restrict__ bsum) {
    __shared__ int lds[512];
    int t = threadIdx.x;
    int v = (t < SCAN_NB) ? bsum[t] : 0;
    lds[t] = v;
    __syncthreads();
    for (int d = 1; d < 512; d <<= 1) {
        int u = (t >= d) ? lds[t - d] : 0;
        __syncthreads();
        lds[t] += u;
        __syncthreads();
    }
    if (t < SCAN_NB) bsum[t] = lds[t] - v;  // exclusive
}

__global__ void k_scan_c(const int* __restrict__ deg, const int* __restrict__ bsum,
                         int* __restrict__ off, int* __restrict__ cur) {
    __shared__ int lds[SCAN_CH];
    int b = blockIdx.x, t = threadIdx.x;
    int i = b * SCAN_CH + t;
    int v = (i < N_RN) ? deg[i] : 0;
    lds[t] = v;
    __syncthreads();
    for (int d = 1; d < SCAN_CH; d <<= 1) {
        int u = (t >= d) ? lds[t - d] : 0;
        __syncthreads();
        lds[t] += u;
        __syncthreads();
    }
    if (i < N_RN) {
        int incl = bsum[b] + lds[t];
        off[i + 1] = incl;
        cur[i] = incl - v;
        if (i == 0) off[0] = 0;
    }
}

// edge-balanced static wave schedule: lb[i] = first node with off[node] >= i*E/NWAVES
__global__ void k_bounds(const int* __restrict__ off, int* __restrict__ lb) {
    int i = blockIdx.x * blockDim.x + threadIdx.x;
    if (i > NWAVES) return;
    if (i == NWAVES) { lb[i] = N_RN; return; }
    size_t t = (size_t)i * N_ED / NWAVES;
    int lo = 0, hi = N_RN;
    while (lo < hi) { int mid = (lo + hi) >> 1; if ((size_t)off[mid] < t) lo = mid + 1; else hi = mid; }
    lb[i] = lo;
}

// inverted scatter step 1: only a 4B index is scattered
__global__ void k_scatter_idx(const int* __restrict__ dst,
                              int* __restrict__ cur,
                              int* __restrict__ eperm) {
    int k = blockIdx.x * blockDim.x + threadIdx.x;
    if (k >= N_ED) return;
    int pos = atomicAdd(cur + dst[k], 1);
    eperm[pos] = k;
}

// inverted scatter step 2: coalesced writes, gathered reads (L3-absorbed)
__global__ void k_permute(const int* __restrict__ eperm,
                          const int* __restrict__ src,
                          const float* __restrict__ r_edge,
                          int* __restrict__ src_perm,
                          float* __restrict__ r16_perm) {
    int pos = blockIdx.x * blockDim.x + threadIdx.x;
    if (pos >= N_ED) return;
    int k = eperm[pos];
    src_perm[pos] = src[k];
    const float4* row = (const float4*)(r_edge + (size_t)k * 16);
    float4 r0 = row[0], r1 = row[1], r2 = row[2], r3 = row[3];
    float4* o = (float4*)(r16_perm + (size_t)pos * 16);
    o[0] = r0; o[1] = r1; o[2] = r2; o[3] = r3;
}

// fused per-layer conv: 4 nodes per wave-iteration (16-lane group per node).
// Static EDGE-BALANCED contiguous node range per wave (lb[] from k_bounds).
// Phase 1: lane-per-edge logits, in-register edge dot. Phase 2: weights
// broadcast via shfl(width 16), gather h rows, unrolled x4.
// Epilogue: group-level 64x64 matvec from LDS-staged agg row.
__global__ void k_layer(const float* __restrict__ h_in,
                        const float* __restrict__ hs, const float* __restrict__ hd,
                        const int* __restrict__ off,
                        const int* __restrict__ lb,
                        const int* __restrict__ src_perm,
                        const float* __restrict__ r16_perm,
                        const float* __restrict__ was_l,   // 16 floats: W_e @ a_e[l]
                        const float* __restrict__ Wm_l,
                        const float* __restrict__ WeWm_l,
                        const float* __restrict__ a_s_n, const float* __restrict__ a_d_n,
                        float* __restrict__ h_out,
                        float* __restrict__ hs_out, float* __restrict__ hd_out) {
    __shared__ float Wl[4096];
    __shared__ float Ww[1024];
    __shared__ float arow[8][4 * 68 + 4];   // 68-pad: groups land on distinct banks
    int tid = threadIdx.x;
    for (int i = tid; i < 4096; i += 512) Wl[i] = Wm_l[i];
    for (int i = tid; i < 1024; i += 512) Ww[i] = WeWm_l[i];
    __syncthreads();
    int lane = tid & 63, w = tid >> 6;
    int g = lane >> 4, lg = lane & 15;
    float wr[16];
#pragma unroll
    for (int t = 0; t < 16; ++t) wr[t] = was_l[t];
    float4 as4 = *(const float4*)&a_s_n[lg << 2];
    float4 ad4 = *(const float4*)&a_d_n[lg << 2];
    int Wv = blockIdx.x * 8 + w;
    int my_lo = lb[Wv], my_hi = lb[Wv + 1];
    for (int nb = my_lo; nb < my_hi; nb += 4) {
        int n = nb + g;
        bool nact = n < my_hi;
        int base = 0, end = 0;
        if (nact) { base = off[n]; end = off[n + 1]; }
        float hdn = nact ? hd[n] : 0.f;
        float m = -1e38f, s = 0.f, racc = 0.f;
        float ax = 0.f, ay = 0.f, az = 0.f, aw = 0.f;
        int nch = (end - base + 15) >> 4;
        int nmax = nch;
        nmax = max(nmax, __shfl_xor(nmax, 16, 64));
        nmax = max(nmax, __shfl_xor(nmax, 32, 64));
        for (int c = 0; c < nmax; ++c) {
            int cb = base + (c << 4);
            int rem = end - cb;
            int cnt = rem > 16 ? 16 : (rem > 0 ? rem : 0);
            float lgt = -1e38f;
            float wvv = 0.f;
            int sk = 0;
            bool act = lg < cnt;
            if (act) {
                int pos = cb + lg;
                sk = src_perm[pos];
                const float4* rp = (const float4*)(r16_perm + (size_t)pos * 16);
                float4 r0 = rp[0], r1 = rp[1], r2 = rp[2], r3 = rp[3];
                float ep = r0.x * wr[0] + r0.y * wr[1] + r0.z * wr[2] + r0.w * wr[3]
                         + r1.x * wr[4] + r1.y * wr[5] + r1.z * wr[6] + r1.w * wr[7]
                         + r2.x * wr[8] + r2.y * wr[9] + r2.z * wr[10] + r2.w * wr[11]
                         + r3.x * wr[12] + r3.y * wr[13] + r3.z * wr[14] + r3.w * wr[15];
                lgt = lrelu(hs[sk] + hdn + ep);
            }
            float cm = lgt;
            cm = fmaxf(cm, __shfl_xor(cm, 1, 16));
            cm = fmaxf(cm, __shfl_xor(cm, 2, 16));
            cm = fmaxf(cm, __shfl_xor(cm, 4, 16));
            cm = fmaxf(cm, __shfl_xor(cm, 8, 16));
            float newm = fmaxf(m, cm);
            float scale = (m > -1e37f) ? __expf(m - newm) : 0.f;
            s *= scale; racc *= scale;
            ax *= scale; ay *= scale; az *= scale; aw *= scale;
            m = newm;
            if (act) wvv = __expf(lgt - m);
            s += wvv;
            // phase 2: unrolled x4; lane lg accumulates dims 4lg..4lg+3
            const float* hb = h_in;
            int e = 0;
            for (; e + 3 < cnt; e += 4) {
                float w0 = __shfl(wvv, e, 16);
                float w1 = __shfl(wvv, e + 1, 16);
                float w2 = __shfl(wvv, e + 2, 16);
                float w3 = __shfl(wvv, e + 3, 16);
                int   s0 = __shfl(sk, e, 16);
                int   s1 = __shfl(sk, e + 1, 16);
                int   s2 = __shfl(sk, e + 2, 16);
                int   s3 = __shfl(sk, e + 3, 16);
                const float4 h0v = *(const float4*)(hb + (size_t)s0 * 64 + (lg << 2));
                const float4 h1v = *(const float4*)(hb + (size_t)s1 * 64 + (lg << 2));
                const float4 h2v = *(const float4*)(hb + (size_t)s2 * 64 + (lg << 2));
                const float4 h3v = *(const float4*)(hb + (size_t)s3 * 64 + (lg << 2));
                float q0 = r16_perm[(size_t)(cb + e) * 16 + lg];
                float q1 = r16_perm[(size_t)(cb + e + 1) * 16 + lg];
                float q2 = r16_perm[(size_t)(cb + e + 2) * 16 + lg];
                float q3 = r16_perm[(size_t)(cb + e + 3) * 16 + lg];
                ax += w0 * h0v.x + w1 * h1v.x + w2 * h2v.x + w3 * h3v.x;
                ay += w0 * h0v.y + w1 * h1v.y + w2 * h2v.y + w3 * h3v.y;
                az += w0 * h0v.z + w1 * h1v.z + w2 * h2v.z + w3 * h3v.z;
                aw += w0 * h0v.w + w1 * h1v.w + w2 * h2v.w + w3 * h3v.w;
                racc += w0 * q0 + w1 * q1 + w2 * q2 + w3 * q3;
            }
            for (; e < cnt; ++e) {
                float w0 = __shfl(wvv, e, 16);
                int   s0 = __shfl(sk, e, 16);
                const float4 h0v = *(const float4*)(hb + (size_t)s0 * 64 + (lg << 2));
                float q0 = r16_perm[(size_t)(cb + e) * 16 + lg];
                ax += w0 * h0v.x; ay += w0 * h0v.y;
                az += w0 * h0v.z; aw += w0 * h0v.w;
                racc += w0 * q0;
            }
        }
        // softmax denominator (group sum)
        s += __shfl_xor(s, 1, 16);
        s += __shfl_xor(s, 2, 16);
        s += __shfl_xor(s, 4, 16);
        s += __shfl_xor(s, 8, 16);
        float inv = (end > base) ? 1.f / s : 0.f;
        // stage normalized agg row for the group matvec
        float* ar = &arow[w][g * 68];
        *(float4*)&ar[lg << 2] = make_float4(ax * inv, ay * inv, az * inv, aw * inv);
        float mx = 0.f, my = 0.f, mz = 0.f, mw = 0.f;
#pragma unroll
        for (int d4 = 0; d4 < 16; ++d4) {
            float4 a = *(const float4*)&ar[d4 << 2];      // LDS broadcast within group
            const float* wl = &Wl[(d4 << 2) * 64 + (lg << 2)];
            float4 w0 = *(const float4*)&wl[0];
            float4 w1 = *(const float4*)&wl[64];
            float4 w2 = *(const float4*)&wl[128];
            float4 w3 = *(const float4*)&wl[192];
            mx += a.x * w0.x + a.y * w1.x + a.z * w2.x + a.w * w3.x;
            my += a.x * w0.y + a.y * w1.y + a.z * w2.y + a.w * w3.y;
            mz += a.x * w0.z + a.y * w1.z + a.z * w2.z + a.w * w3.z;
            mw += a.x * w0.w + a.y * w1.w + a.z * w2.w + a.w * w3.w;
        }
        float rs = racc * inv;
#pragma unroll
        for (int t = 0; t < 16; ++t) {
            float rt = __shfl(rs, t, 16);
            const float4 wt = *(const float4*)&Ww[t * 64 + (lg << 2)];
            mx += rt * wt.x; my += rt * wt.y; mz += rt * wt.z; mw += rt * wt.w;
        }
        if (nact) {
            const float4 hi4 = *(const float4*)(h_in + (size_t)n * 64 + (lg << 2));
            float4 hv;
            hv.x = lrelu(hi4.x + mx); hv.y = lrelu(hi4.y + my);
            hv.z = lrelu(hi4.z + mz); hv.w = lrelu(hi4.w + mw);
            *(float4*)(h_out + (size_t)n * 64 + (lg << 2)) = hv;
            float x = hv.x * as4.x + hv.y * as4.y + hv.z * as4.z + hv.w * as4.w;
            float y = hv.x * ad4.x + hv.y * ad4.y + hv.z * ad4.z + hv.w * ad4.w;
            x += __shfl_xor(x, 1, 16); x += __shfl_xor(x, 2, 16);
            x += __shfl_xor(x, 4, 16); x += __shfl_xor(x, 8, 16);
            y += __shfl_xor(y, 1, 16); y += __shfl_xor(y, 2, 16);
            y += __shfl_xor(y, 4, 16); y += __shfl_xor(y, 8, 16);
            if (lg == 0) { hs_out[n] = x; hd_out[n] = y; }
        }
    }
}

// block per graph readout (graph_id sorted -> contiguous ranges via binary search)
__global__ void k_readout(const float* __restrict__ h,
                          const float* __restrict__ d_edge,
                          const int* __restrict__ graph_id,
                          const float* __restrict__ i_node,
                          const float* __restrict__ W_i,
                          const float* __restrict__ w_d,
                          const float* __restrict__ b_d,
                          const float* __restrict__ W_mlp,
                          const float* __restrict__ b_mlp,
                          const float* __restrict__ W_out,
                          const float* __restrict__ b_out,
                          float* __restrict__ out) {
    int g = blockIdx.x, j = threadIdx.x;
    int lo = 0, hi = N_RN;
    while (lo < hi) { int mid = (lo + hi) >> 1; if (graph_id[mid] < g) lo = mid + 1; else hi = mid; }
    int start = lo;
    hi = N_RN;
    while (lo < hi) { int mid = (lo + hi) >> 1; if (graph_id[mid] < g + 1) lo = mid + 1; else hi = mid; }
    int end = lo;

    float wd = w_d[0], bd = b_d[0];
    float acc0 = 0.f, acc1 = 0.f, sg = 0.f;
    for (int n = start; n < end; ++n) {
        float hv = h[(size_t)n * 64 + j];
        float de = d_edge[n];
        float gate = 1.f / (1.f + __expf(-(de * wd + bd)));
        acc0 += hv;
        acc1 += gate * hv;
        sg += gate;
    }
    float hij = i_node[g] * W_i[j] + acc1;
    float pooled = acc0 + sg * hij;

    __shared__ float xa[64], xb[64];
    xa[j] = pooled;
    __syncthreads();
#pragma unroll
    for (int layer = 0; layer < 3; ++layer) {
        const float* W = W_mlp + layer * 4096;
        float* srcb = (layer & 1) ? xb : xa;
        float* dstb = (layer & 1) ? xa : xb;
        float acc = b_mlp[layer * 64 + j];
        for (int d = 0; d < 64; ++d) acc += srcb[d] * W[d * 64 + j];
        acc = fmaxf(acc, 0.f);
        __syncthreads();
        dstb[j] = acc;
        __syncthreads();
    }
    float v = xb[j] * W_out[j];
#pragma unroll
    for (int off = 32; off; off >>= 1) v += __shfl_xor(v, off, 64);
    if (j == 0) out[g] = v + b_out[0];
}

extern "C" void kernel_launch(void* const* d_in, const int* in_sizes, int n_in,
                              void* d_out, int out_size, void* d_ws, size_t ws_size,
                              hipStream_t stream) {
    const float* r_node  = (const float*)d_in[0];
    const float* i_node  = (const float*)d_in[1];
    const float* r_edge  = (const float*)d_in[2];
    const float* d_edge  = (const float*)d_in[3];
    const int*   r2r_src = (const int*)d_in[4];
    const int*   r2r_dst = (const int*)d_in[5];
    const int*   graph_id= (const int*)d_in[6];
    const float* W_r     = (const float*)d_in[7];
    const float* W_i     = (const float*)d_in[8];
    const float* W_e     = (const float*)d_in[9];
    const float* Wm      = (const float*)d_in[10];
    const float* a_s     = (const float*)d_in[11];
    const float* a_d     = (const float*)d_in[12];
    const float* a_e     = (const float*)d_in[13];
    const float* w_d     = (const float*)d_in[14];
    const float* b_d     = (const float*)d_in[15];
    const float* W_mlp   = (const float*)d_in[16];
    const float* b_mlp   = (const float*)d_in[17];
    const float* W_out   = (const float*)d_in[18];
    const float* b_out   = (const float*)d_in[19];
    float* out = (float*)d_out;

    float* ws = (float*)d_ws;
    float* h0   = ws;                                  // N*64
    float* h1   = h0 + (size_t)N_RN * 64;              // N*64
    float* hs0  = h1 + (size_t)N_RN * 64;              // N
    float* hd0  = hs0 + N_RN;                          // N
    float* hs1  = hd0 + N_RN;                          // N
    float* hd1  = hs1 + N_RN;                          // N
    float* WeWm = hd1 + N_RN;                          // 4*16*64
    float* wasb = WeWm + 4096;                         // 4*16
    int*   deg  = (int*)(wasb + 64);                   // N
    int*   offs = deg + N_RN;                          // N+1
    int*   cur  = offs + N_RN + 1;                     // N
    int*   bsum = cur + N_RN;                          // 512
    int*   lb   = bsum + 512;                          // NWAVES+1
    int*   eperm= lb + NWAVES + 1;                     // E
    int*   src_perm = eperm + N_ED;                    // E
    float* r16_perm = (float*)(src_perm + N_ED);       // 16*E

    k_embed_h<<<2048, 256, 0, stream>>>(r_node, W_r, a_s, a_d, h0, hs0, hd0);
    k_wewm<<<17, 256, 0, stream>>>(W_e, Wm, a_e, WeWm, wasb);

    hipMemsetAsync(deg, 0, N_RN * sizeof(int), stream);
    k_hist<<<(N_ED + 255) / 256, 256, 0, stream>>>(r2r_dst, deg);
    k_scan_a<<<SCAN_NB, SCAN_CH, 0, stream>>>(deg, bsum);
    k_scan_b<<<1, 512, 0, stream>>>(bsum);
    k_scan_c<<<SCAN_NB, SCAN_CH, 0, stream>>>(deg, bsum, offs, cur);
    k_bounds<<<(NWAVES + 256) / 256, 256, 0, stream>>>(offs, lb);
    k_scatter_idx<<<(N_ED + 255) / 256, 256, 0, stream>>>(r2r_dst, cur, eperm);
    k_permute<<<(N_ED + 255) / 256, 256, 0, stream>>>(eperm, r2r_src, r_edge,
                                                      src_perm, r16_perm);

    float* hin = h0;  float* hout = h1;
    float* hsi = hs0; float* hdi = hd0;
    float* hso = hs1; float* hdo = hd1;
    for (int l = 0; l < 4; ++l) {
        int ln = (l + 1) & 3;
        k_layer<<<1024, 512, 0, stream>>>(hin, hsi, hdi, offs, lb, src_perm, r16_perm,
                                          wasb + l * 16, Wm + l * 4096, WeWm + l * 1024,
                                          a_s + ln * 64, a_d + ln * 64,
                                          hout, hso, hdo);
        float* t;
        t = hin; hin = hout; hout = t;
        t = hsi; hsi = hso; hso = t;
        t = hdi; hdi = hdo; hdo = t;
    }

    k_readout<<<N_G, 64, 0, stream>>>(hin, d_edge, graph_id, i_node, W_i, w_d, b_d,
                                      W_mlp, b_mlp, W_out, b_out, out);
}

// Round 6
// 781.361 us; speedup vs baseline: 2.1431x; 1.0455x over previous
//
#include <hip/hip_runtime.h>
#include <math.h>

#define N_RN 100000
#define N_ED 1200000
#define N_G  4096
#define SCAN_CH 256
#define SCAN_NB ((N_RN + SCAN_CH - 1) / SCAN_CH)   // 391

__device__ __forceinline__ float lrelu(float x) { return x > 0.f ? x : 0.1f * x; }

// h = r_node @ W_r (wave/node, lane=col, row via coalesced LDS); fused hs/hd layer0
__global__ void k_embed_h(const float* __restrict__ r_node,
                          const float* __restrict__ W_r,
                          const float* __restrict__ a_s0,
                          const float* __restrict__ a_d0,
                          float* __restrict__ h,
                          float* __restrict__ hs, float* __restrict__ hd) {
    __shared__ float Wl[64 * 64];
    __shared__ float arow[4][64];
    int tid = threadIdx.x;
    for (int i = tid; i < 4096; i += 256) Wl[i] = W_r[i];
    __syncthreads();
    int lane = tid & 63, w = tid >> 6;
    float asj = a_s0[lane], adj = a_d0[lane];
    int wid = blockIdx.x * 4 + w;
    int nw = gridDim.x * 4;
    for (int n = wid; n < N_RN; n += nw) {
        arow[w][lane] = r_node[(size_t)n * 64 + lane];
        float acc = 0.f;
#pragma unroll
        for (int d4 = 0; d4 < 16; ++d4) {
            float4 a = *(const float4*)&arow[w][d4 * 4];
            int d = d4 * 4;
            acc += a.x * Wl[(d + 0) * 64 + lane];
            acc += a.y * Wl[(d + 1) * 64 + lane];
            acc += a.z * Wl[(d + 2) * 64 + lane];
            acc += a.w * Wl[(d + 3) * 64 + lane];
        }
        h[(size_t)n * 64 + lane] = acc;
        float x = acc * asj, y = acc * adj;
#pragma unroll
        for (int off = 32; off; off >>= 1) {
            x += __shfl_xor(x, off, 64);
            y += __shfl_xor(y, off, 64);
        }
        if (lane == 0) { hs[n] = x; hd[n] = y; }
    }
}

// WeWm[l] = W_e @ Wm[l]  (16x64 per layer); also was_all[l][t] = W_e[t,:] . a_e[l]
__global__ void k_wewm(const float* __restrict__ W_e,
                       const float* __restrict__ Wm,
                       const float* __restrict__ a_e,
                       float* __restrict__ WeWm,
                       float* __restrict__ was_all) {
    int idx = blockIdx.x * blockDim.x + threadIdx.x;   // 17*256
    if (idx < 4096) {
        int l = idx >> 10, rem = idx & 1023;
        int t = rem >> 6, j = rem & 63;
        float acc = 0.f;
        for (int d = 0; d < 64; ++d)
            acc += W_e[t * 64 + d] * Wm[l * 4096 + d * 64 + j];
        WeWm[idx] = acc;
    } else {
        int r = idx - 4096;
        if (r < 64) {
            int l = r >> 4, t = r & 15;
            float acc = 0.f;
            for (int j = 0; j < 64; ++j)
                acc += W_e[t * 64 + j] * a_e[l * 64 + j];
            was_all[r] = acc;
        }
    }
}

// ---- CSR build ----
__global__ void k_hist(const int* __restrict__ dst, int* __restrict__ deg) {
    int k = blockIdx.x * blockDim.x + threadIdx.x;
    if (k < N_ED) atomicAdd(deg + dst[k], 1);
}

__global__ void k_scan_a(const int* __restrict__ deg, int* __restrict__ bsum) {
    __shared__ int lds[SCAN_CH];
    int b = blockIdx.x, t = threadIdx.x;
    int i = b * SCAN_CH + t;
    int v = (i < N_RN) ? deg[i] : 0;
    lds[t] = v;
    __syncthreads();
    for (int d = 128; d; d >>= 1) {
        if (t < d) lds[t] += lds[t + d];
        __syncthreads();
    }
    if (t == 0) bsum[b] = lds[0];
}

__global__ void k_scan_b(int* __restrict__ bsum) {
    __shared__ int lds[512];
    int t = threadIdx.x;
    int v = (t < SCAN_NB) ? bsum[t] : 0;
    lds[t] = v;
    __syncthreads();
    for (int d = 1; d < 512; d <<= 1) {
        int u = (t >= d) ? lds[t - d] : 0;
        __syncthreads();
        lds[t] += u;
        __syncthreads();
    }
    if (t < SCAN_NB) bsum[t] = lds[t] - v;  // exclusive
}

__global__ void k_scan_c(const int* __restrict__ deg, const int* __restrict__ bsum,
                         int* __restrict__ off, int* __restrict__ cur) {
    __shared__ int lds[SCAN_CH];
    int b = blockIdx.x, t = threadIdx.x;
    int i = b * SCAN_CH + t;
    int v = (i < N_RN) ? deg[i] : 0;
    lds[t] = v;
    __syncthreads();
    for (int d = 1; d < SCAN_CH; d <<= 1) {
        int u = (t >= d) ? lds[t - d] : 0;
        __syncthreads();
        lds[t] += u;
        __syncthreads();
    }
    if (i < N_RN) {
        int incl = bsum[b] + lds[t];
        off[i + 1] = incl;
        cur[i] = incl - v;
        if (i == 0) off[0] = 0;
    }
}

// inverted scatter step 1: only a 4B index is scattered
__global__ void k_scatter_idx(const int* __restrict__ dst,
                              int* __restrict__ cur,
                              int* __restrict__ eperm) {
    int k = blockIdx.x * blockDim.x + threadIdx.x;
    if (k >= N_ED) return;
    int pos = atomicAdd(cur + dst[k], 1);
    eperm[pos] = k;
}

// inverted scatter step 2: coalesced writes, gathered reads (L3-absorbed).
// Also precomputes per-layer edge-logit e-terms: elog[l][pos] = r16 . (W_e@a_e[l])
__global__ void k_permute(const int* __restrict__ eperm,
                          const int* __restrict__ src,
                          const float* __restrict__ r_edge,
                          const float* __restrict__ was_all,  // 4x16
                          int* __restrict__ src_perm,
                          float* __restrict__ r16_perm,
                          float* __restrict__ elog) {
    int pos = blockIdx.x * blockDim.x + threadIdx.x;
    if (pos >= N_ED) return;
    int k = eperm[pos];
    src_perm[pos] = src[k];
    const float4* row = (const float4*)(r_edge + (size_t)k * 16);
    float4 r0 = row[0], r1 = row[1], r2 = row[2], r3 = row[3];
    float4* o = (float4*)(r16_perm + (size_t)pos * 16);
    o[0] = r0; o[1] = r1; o[2] = r2; o[3] = r3;
#pragma unroll
    for (int l = 0; l < 4; ++l) {
        const float* wa = was_all + l * 16;   // uniform -> scalar loads
        float e = r0.x * wa[0] + r0.y * wa[1] + r0.z * wa[2] + r0.w * wa[3]
                + r1.x * wa[4] + r1.y * wa[5] + r1.z * wa[6] + r1.w * wa[7]
                + r2.x * wa[8] + r2.y * wa[9] + r2.z * wa[10] + r2.w * wa[11]
                + r3.x * wa[12] + r3.y * wa[13] + r3.z * wa[14] + r3.w * wa[15];
        elog[(size_t)l * N_ED + pos] = e;
    }
}

// fused per-layer conv: 4 nodes per wave-iteration (16-lane group per node),
// static strided schedule (R3-proven). Phase 1: lane-per-edge logit from
// PRECOMPUTED elog (no r16 row load on critical path). Phase 2: weights
// broadcast via shfl(width 16), gather h rows, unrolled x4.
// Epilogue: group-level 64x64 matvec from LDS-staged agg row.
__global__ void k_layer(const float* __restrict__ h_in,
                        const float* __restrict__ hs, const float* __restrict__ hd,
                        const int* __restrict__ off,
                        const int* __restrict__ src_perm,
                        const float* __restrict__ r16_perm,
                        const float* __restrict__ elog_l,  // N_ED floats, this layer
                        const float* __restrict__ Wm_l,
                        const float* __restrict__ WeWm_l,
                        const float* __restrict__ a_s_n, const float* __restrict__ a_d_n,
                        float* __restrict__ h_out,
                        float* __restrict__ hs_out, float* __restrict__ hd_out) {
    __shared__ float Wl[4096];
    __shared__ float Ww[1024];
    __shared__ float arow[8][4 * 68 + 4];   // 68-pad: groups land on distinct banks
    int tid = threadIdx.x;
    for (int i = tid; i < 4096; i += 512) Wl[i] = Wm_l[i];
    for (int i = tid; i < 1024; i += 512) Ww[i] = WeWm_l[i];
    __syncthreads();
    int lane = tid & 63, w = tid >> 6;
    int g = lane >> 4, lg = lane & 15;
    float4 as4 = *(const float4*)&a_s_n[lg << 2];
    float4 ad4 = *(const float4*)&a_d_n[lg << 2];
    int Wv = blockIdx.x * 8 + w;
    int NW = gridDim.x * 8;
    for (int nb = Wv * 4; nb < N_RN; nb += NW * 4) {
        int n = nb + g;
        bool nact = n < N_RN;
        int base = 0, end = 0;
        if (nact) { base = off[n]; end = off[n + 1]; }
        float hdn = nact ? hd[n] : 0.f;
        float m = -1e38f, s = 0.f, racc = 0.f;
        float ax = 0.f, ay = 0.f, az = 0.f, aw = 0.f;
        int nch = (end - base + 15) >> 4;
        int nmax = nch;
        nmax = max(nmax, __shfl_xor(nmax, 16, 64));
        nmax = max(nmax, __shfl_xor(nmax, 32, 64));
        for (int c = 0; c < nmax; ++c) {
            int cb = base + (c << 4);
            int rem = end - cb;
            int cnt = rem > 16 ? 16 : (rem > 0 ? rem : 0);
            float lgt = -1e38f;
            float wvv = 0.f;
            int sk = 0;
            bool act = lg < cnt;
            if (act) {
                int pos = cb + lg;
                sk = src_perm[pos];
                float ep = elog_l[pos];
                lgt = lrelu(hs[sk] + hdn + ep);
            }
            float cm = lgt;
            cm = fmaxf(cm, __shfl_xor(cm, 1, 16));
            cm = fmaxf(cm, __shfl_xor(cm, 2, 16));
            cm = fmaxf(cm, __shfl_xor(cm, 4, 16));
            cm = fmaxf(cm, __shfl_xor(cm, 8, 16));
            float newm = fmaxf(m, cm);
            float scale = (m > -1e37f) ? __expf(m - newm) : 0.f;
            s *= scale; racc *= scale;
            ax *= scale; ay *= scale; az *= scale; aw *= scale;
            m = newm;
            if (act) wvv = __expf(lgt - m);
            s += wvv;
            // phase 2: unrolled x4; lane lg accumulates dims 4lg..4lg+3
            const float* hb = h_in;
            int e = 0;
            for (; e + 3 < cnt; e += 4) {
                float w0 = __shfl(wvv, e, 16);
                float w1 = __shfl(wvv, e + 1, 16);
                float w2 = __shfl(wvv, e + 2, 16);
                float w3 = __shfl(wvv, e + 3, 16);
                int   s0 = __shfl(sk, e, 16);
                int   s1 = __shfl(sk, e + 1, 16);
                int   s2 = __shfl(sk, e + 2, 16);
                int   s3 = __shfl(sk, e + 3, 16);
                const float4 h0v = *(const float4*)(hb + (size_t)s0 * 64 + (lg << 2));
                const float4 h1v = *(const float4*)(hb + (size_t)s1 * 64 + (lg << 2));
                const float4 h2v = *(const float4*)(hb + (size_t)s2 * 64 + (lg << 2));
                const float4 h3v = *(const float4*)(hb + (size_t)s3 * 64 + (lg << 2));
                float q0 = r16_perm[(size_t)(cb + e) * 16 + lg];
                float q1 = r16_perm[(size_t)(cb + e + 1) * 16 + lg];
                float q2 = r16_perm[(size_t)(cb + e + 2) * 16 + lg];
                float q3 = r16_perm[(size_t)(cb + e + 3) * 16 + lg];
                ax += w0 * h0v.x + w1 * h1v.x + w2 * h2v.x + w3 * h3v.x;
                ay += w0 * h0v.y + w1 * h1v.y + w2 * h2v.y + w3 * h3v.y;
                az += w0 * h0v.z + w1 * h1v.z + w2 * h2v.z + w3 * h3v.z;
                aw += w0 * h0v.w + w1 * h1v.w + w2 * h2v.w + w3 * h3v.w;
                racc += w0 * q0 + w1 * q1 + w2 * q2 + w3 * q3;
            }
            for (; e < cnt; ++e) {
                float w0 = __shfl(wvv, e, 16);
                int   s0 = __shfl(sk, e, 16);
                const float4 h0v = *(const float4*)(hb + (size_t)s0 * 64 + (lg << 2));
                float q0 = r16_perm[(size_t)(cb + e) * 16 + lg];
                ax += w0 * h0v.x; ay += w0 * h0v.y;
                az += w0 * h0v.z; aw += w0 * h0v.w;
                racc += w0 * q0;
            }
        }
        // softmax denominator (group sum)
        s += __shfl_xor(s, 1, 16);
        s += __shfl_xor(s, 2, 16);
        s += __shfl_xor(s, 4, 16);
        s += __shfl_xor(s, 8, 16);
        float inv = (end > base) ? 1.f / s : 0.f;
        // stage normalized agg row for the group matvec
        float* ar = &arow[w][g * 68];
        *(float4*)&ar[lg << 2] = make_float4(ax * inv, ay * inv, az * inv, aw * inv);
        float mx = 0.f, my = 0.f, mz = 0.f, mw = 0.f;
#pragma unroll
        for (int d4 = 0; d4 < 16; ++d4) {
            float4 a = *(const float4*)&ar[d4 << 2];      // LDS broadcast within group
            const float* wl = &Wl[(d4 << 2) * 64 + (lg << 2)];
            float4 w0 = *(const float4*)&wl[0];
            float4 w1 = *(const float4*)&wl[64];
            float4 w2 = *(const float4*)&wl[128];
            float4 w3 = *(const float4*)&wl[192];
            mx += a.x * w0.x + a.y * w1.x + a.z * w2.x + a.w * w3.x;
            my += a.x * w0.y + a.y * w1.y + a.z * w2.y + a.w * w3.y;
            mz += a.x * w0.z + a.y * w1.z + a.z * w2.z + a.w * w3.z;
            mw += a.x * w0.w + a.y * w1.w + a.z * w2.w + a.w * w3.w;
        }
        float rs = racc * inv;
#pragma unroll
        for (int t = 0; t < 16; ++t) {
            float rt = __shfl(rs, t, 16);
            const float4 wt = *(const float4*)&Ww[t * 64 + (lg << 2)];
            mx += rt * wt.x; my += rt * wt.y; mz += rt * wt.z; mw += rt * wt.w;
        }
        if (nact) {
            const float4 hi4 = *(const float4*)(h_in + (size_t)n * 64 + (lg << 2));
            float4 hv;
            hv.x = lrelu(hi4.x + mx); hv.y = lrelu(hi4.y + my);
            hv.z = lrelu(hi4.z + mz); hv.w = lrelu(hi4.w + mw);
            *(float4*)(h_out + (size_t)n * 64 + (lg << 2)) = hv;
            float x = hv.x * as4.x + hv.y * as4.y + hv.z * as4.z + hv.w * as4.w;
            float y = hv.x * ad4.x + hv.y * ad4.y + hv.z * ad4.z + hv.w * ad4.w;
            x += __shfl_xor(x, 1, 16); x += __shfl_xor(x, 2, 16);
            x += __shfl_xor(x, 4, 16); x += __shfl_xor(x, 8, 16);
            y += __shfl_xor(y, 1, 16); y += __shfl_xor(y, 2, 16);
            y += __shfl_xor(y, 4, 16); y += __shfl_xor(y, 8, 16);
            if (lg == 0) { hs_out[n] = x; hd_out[n] = y; }
        }
    }
}

// block per graph readout (graph_id sorted -> contiguous ranges via binary search)
__global__ void k_readout(const float* __restrict__ h,
                          const float* __restrict__ d_edge,
                          const int* __restrict__ graph_id,
                          const float* __restrict__ i_node,
                          const float* __restrict__ W_i,
                          const float* __restrict__ w_d,
                          const float* __restrict__ b_d,
                          const float* __restrict__ W_mlp,
                          const float* __restrict__ b_mlp,
                          const float* __restrict__ W_out,
                          const float* __restrict__ b_out,
                          float* __restrict__ out) {
    int g = blockIdx.x, j = threadIdx.x;
    int lo = 0, hi = N_RN;
    while (lo < hi) { int mid = (lo + hi) >> 1; if (graph_id[mid] < g) lo = mid + 1; else hi = mid; }
    int start = lo;
    hi = N_RN;
    while (lo < hi) { int mid = (lo + hi) >> 1; if (graph_id[mid] < g + 1) lo = mid + 1; else hi = mid; }
    int end = lo;

    float wd = w_d[0], bd = b_d[0];
    float acc0 = 0.f, acc1 = 0.f, sg = 0.f;
    for (int n = start; n < end; ++n) {
        float hv = h[(size_t)n * 64 + j];
        float de = d_edge[n];
        float gate = 1.f / (1.f + __expf(-(de * wd + bd)));
        acc0 += hv;
        acc1 += gate * hv;
        sg += gate;
    }
    float hij = i_node[g] * W_i[j] + acc1;
    float pooled = acc0 + sg * hij;

    __shared__ float xa[64], xb[64];
    xa[j] = pooled;
    __syncthreads();
#pragma unroll
    for (int layer = 0; layer < 3; ++layer) {
        const float* W = W_mlp + layer * 4096;
        float* srcb = (layer & 1) ? xb : xa;
        float* dstb = (layer & 1) ? xa : xb;
        float acc = b_mlp[layer * 64 + j];
        for (int d = 0; d < 64; ++d) acc += srcb[d] * W[d * 64 + j];
        acc = fmaxf(acc, 0.f);
        __syncthreads();
        dstb[j] = acc;
        __syncthreads();
    }
    float v = xb[j] * W_out[j];
#pragma unroll
    for (int off = 32; off; off >>= 1) v += __shfl_xor(v, off, 64);
    if (j == 0) out[g] = v + b_out[0];
}

extern "C" void kernel_launch(void* const* d_in, const int* in_sizes, int n_in,
                              void* d_out, int out_size, void* d_ws, size_t ws_size,
                              hipStream_t stream) {
    const float* r_node  = (const float*)d_in[0];
    const float* i_node  = (const float*)d_in[1];
    const float* r_edge  = (const float*)d_in[2];
    const float* d_edge  = (const float*)d_in[3];
    const int*   r2r_src = (const int*)d_in[4];
    const int*   r2r_dst = (const int*)d_in[5];
    const int*   graph_id= (const int*)d_in[6];
    const float* W_r     = (const float*)d_in[7];
    const float* W_i     = (const float*)d_in[8];
    const float* W_e     = (const float*)d_in[9];
    const float* Wm      = (const float*)d_in[10];
    const float* a_s     = (const float*)d_in[11];
    const float* a_d     = (const float*)d_in[12];
    const float* a_e     = (const float*)d_in[13];
    const float* w_d     = (const float*)d_in[14];
    const float* b_d     = (const float*)d_in[15];
    const float* W_mlp   = (const float*)d_in[16];
    const float* b_mlp   = (const float*)d_in[17];
    const float* W_out   = (const float*)d_in[18];
    const float* b_out   = (const float*)d_in[19];
    float* out = (float*)d_out;

    float* ws = (float*)d_ws;
    float* h0   = ws;                                  // N*64
    float* h1   = h0 + (size_t)N_RN * 64;              // N*64
    float* hs0  = h1 + (size_t)N_RN * 64;              // N
    float* hd0  = hs0 + N_RN;                          // N
    float* hs1  = hd0 + N_RN;                          // N
    float* hd1  = hs1 + N_RN;                          // N
    float* WeWm = hd1 + N_RN;                          // 4*16*64
    float* wasb = WeWm + 4096;                         // 4*16
    int*   deg  = (int*)(wasb + 64);                   // N
    int*   offs = deg + N_RN;                          // N+1
    int*   cur  = offs + N_RN + 1;                     // N
    int*   bsum = cur + N_RN;                          // 512
    int*   eperm= bsum + 512;                          // E
    int*   src_perm = eperm + N_ED;                    // E
    float* elog = (float*)(src_perm + N_ED);           // 4*E
    float* r16_perm = elog + (size_t)4 * N_ED;         // 16*E

    k_embed_h<<<2048, 256, 0, stream>>>(r_node, W_r, a_s, a_d, h0, hs0, hd0);
    k_wewm<<<17, 256, 0, stream>>>(W_e, Wm, a_e, WeWm, wasb);

    hipMemsetAsync(deg, 0, N_RN * sizeof(int), stream);
    k_hist<<<(N_ED + 255) / 256, 256, 0, stream>>>(r2r_dst, deg);
    k_scan_a<<<SCAN_NB, SCAN_CH, 0, stream>>>(deg, bsum);
    k_scan_b<<<1, 512, 0, stream>>>(bsum);
    k_scan_c<<<SCAN_NB, SCAN_CH, 0, stream>>>(deg, bsum, offs, cur);
    k_scatter_idx<<<(N_ED + 255) / 256, 256, 0, stream>>>(r2r_dst, cur, eperm);
    k_permute<<<(N_ED + 255) / 256, 256, 0, stream>>>(eperm, r2r_src, r_edge, wasb,
                                                      src_perm, r16_perm, elog);

    float* hin = h0;  float* hout = h1;
    float* hsi = hs0; float* hdi = hd0;
    float* hso = hs1; float* hdo = hd1;
    for (int l = 0; l < 4; ++l) {
        int ln = (l + 1) & 3;
        k_layer<<<1024, 512, 0, stream>>>(hin, hsi, hdi, offs, src_perm, r16_perm,
                                          elog + (size_t)l * N_ED,
                                          Wm + l * 4096, WeWm + l * 1024,
                                          a_s + ln * 64, a_d + ln * 64,
                                          hout, hso, hdo);
        float* t;
        t = hin; hin = hout; hout = t;
        t = hsi; hsi = hso; hso = t;
        t = hdi; hdi = hdo; hdo = t;
    }

    k_readout<<<N_G, 64, 0, stream>>>(hin, d_edge, graph_id, i_node, W_i, w_d, b_d,
                                      W_mlp, b_mlp, W_out, b_out, out);
}

// Round 7
// 776.849 us; speedup vs baseline: 2.1556x; 1.0058x over previous
//
#include <hip/hip_runtime.h>
#include <math.h>

#define N_RN 100000
#define N_ED 1200000
#define N_G  4096
#define SCAN_CH 256
#define SCAN_NB ((N_RN + SCAN_CH - 1) / SCAN_CH)   // 391

__device__ __forceinline__ float lrelu(float x) { return x > 0.f ? x : 0.1f * x; }

// h = r_node @ W_r (wave/node, lane=col, row via coalesced LDS); fused hs/hd layer0
__global__ void k_embed_h(const float* __restrict__ r_node,
                          const float* __restrict__ W_r,
                          const float* __restrict__ a_s0,
                          const float* __restrict__ a_d0,
                          float* __restrict__ h,
                          float* __restrict__ hs, float* __restrict__ hd) {
    __shared__ float Wl[64 * 64];
    __shared__ float arow[4][64];
    int tid = threadIdx.x;
    for (int i = tid; i < 4096; i += 256) Wl[i] = W_r[i];
    __syncthreads();
    int lane = tid & 63, w = tid >> 6;
    float asj = a_s0[lane], adj = a_d0[lane];
    int wid = blockIdx.x * 4 + w;
    int nw = gridDim.x * 4;
    for (int n = wid; n < N_RN; n += nw) {
        arow[w][lane] = r_node[(size_t)n * 64 + lane];
        float acc = 0.f;
#pragma unroll
        for (int d4 = 0; d4 < 16; ++d4) {
            float4 a = *(const float4*)&arow[w][d4 * 4];
            int d = d4 * 4;
            acc += a.x * Wl[(d + 0) * 64 + lane];
            acc += a.y * Wl[(d + 1) * 64 + lane];
            acc += a.z * Wl[(d + 2) * 64 + lane];
            acc += a.w * Wl[(d + 3) * 64 + lane];
        }
        h[(size_t)n * 64 + lane] = acc;
        float x = acc * asj, y = acc * adj;
#pragma unroll
        for (int off = 32; off; off >>= 1) {
            x += __shfl_xor(x, off, 64);
            y += __shfl_xor(y, off, 64);
        }
        if (lane == 0) { hs[n] = x; hd[n] = y; }
    }
}

// WeWm[l] = W_e @ Wm[l]  (16x64 per layer); also was_all[l][t] = W_e[t,:] . a_e[l]
__global__ void k_wewm(const float* __restrict__ W_e,
                       const float* __restrict__ Wm,
                       const float* __restrict__ a_e,
                       float* __restrict__ WeWm,
                       float* __restrict__ was_all) {
    int idx = blockIdx.x * blockDim.x + threadIdx.x;   // 17*256
    if (idx < 4096) {
        int l = idx >> 10, rem = idx & 1023;
        int t = rem >> 6, j = rem & 63;
        float acc = 0.f;
        for (int d = 0; d < 64; ++d)
            acc += W_e[t * 64 + d] * Wm[l * 4096 + d * 64 + j];
        WeWm[idx] = acc;
    } else {
        int r = idx - 4096;
        if (r < 64) {
            int l = r >> 4, t = r & 15;
            float acc = 0.f;
            for (int j = 0; j < 64; ++j)
                acc += W_e[t * 64 + j] * a_e[l * 64 + j];
            was_all[r] = acc;
        }
    }
}

// ---- CSR build ----
__global__ void k_hist(const int* __restrict__ dst, int* __restrict__ deg) {
    int k = blockIdx.x * blockDim.x + threadIdx.x;
    if (k < N_ED) atomicAdd(deg + dst[k], 1);
}

__global__ void k_scan_a(const int* __restrict__ deg, int* __restrict__ bsum) {
    __shared__ int lds[SCAN_CH];
    int b = blockIdx.x, t = threadIdx.x;
    int i = b * SCAN_CH + t;
    int v = (i < N_RN) ? deg[i] : 0;
    lds[t] = v;
    __syncthreads();
    for (int d = 128; d; d >>= 1) {
        if (t < d) lds[t] += lds[t + d];
        __syncthreads();
    }
    if (t == 0) bsum[b] = lds[0];
}

__global__ void k_scan_b(int* __restrict__ bsum) {
    __shared__ int lds[512];
    int t = threadIdx.x;
    int v = (t < SCAN_NB) ? bsum[t] : 0;
    lds[t] = v;
    __syncthreads();
    for (int d = 1; d < 512; d <<= 1) {
        int u = (t >= d) ? lds[t - d] : 0;
        __syncthreads();
        lds[t] += u;
        __syncthreads();
    }
    if (t < SCAN_NB) bsum[t] = lds[t] - v;  // exclusive
}

__global__ void k_scan_c(const int* __restrict__ deg, const int* __restrict__ bsum,
                         int* __restrict__ off, int* __restrict__ cur) {
    __shared__ int lds[SCAN_CH];
    int b = blockIdx.x, t = threadIdx.x;
    int i = b * SCAN_CH + t;
    int v = (i < N_RN) ? deg[i] : 0;
    lds[t] = v;
    __syncthreads();
    for (int d = 1; d < SCAN_CH; d <<= 1) {
        int u = (t >= d) ? lds[t - d] : 0;
        __syncthreads();
        lds[t] += u;
        __syncthreads();
    }
    if (i < N_RN) {
        int incl = bsum[b] + lds[t];
        off[i + 1] = incl;
        cur[i] = incl - v;
        if (i == 0) off[0] = 0;
    }
}

// inverted scatter step 1: only a 4B index is scattered
__global__ void k_scatter_idx(const int* __restrict__ dst,
                              int* __restrict__ cur,
                              int* __restrict__ eperm) {
    int k = blockIdx.x * blockDim.x + threadIdx.x;
    if (k >= N_ED) return;
    int pos = atomicAdd(cur + dst[k], 1);
    eperm[pos] = k;
}

// inverted scatter step 2: coalesced writes, gathered reads (L3-absorbed).
// Emits packed per-layer (src, elog) int2 planes: one 8B load in k_layer phase 1.
__global__ void k_permute(const int* __restrict__ eperm,
                          const int* __restrict__ src,
                          const float* __restrict__ r_edge,
                          const float* __restrict__ was_all,  // 4x16
                          int2* __restrict__ se,
                          float* __restrict__ r16_perm) {
    int pos = blockIdx.x * blockDim.x + threadIdx.x;
    if (pos >= N_ED) return;
    int k = eperm[pos];
    int sk = src[k];
    const float4* row = (const float4*)(r_edge + (size_t)k * 16);
    float4 r0 = row[0], r1 = row[1], r2 = row[2], r3 = row[3];
    float4* o = (float4*)(r16_perm + (size_t)pos * 16);
    o[0] = r0; o[1] = r1; o[2] = r2; o[3] = r3;
#pragma unroll
    for (int l = 0; l < 4; ++l) {
        const float* wa = was_all + l * 16;   // uniform -> scalar loads
        float e = r0.x * wa[0] + r0.y * wa[1] + r0.z * wa[2] + r0.w * wa[3]
                + r1.x * wa[4] + r1.y * wa[5] + r1.z * wa[6] + r1.w * wa[7]
                + r2.x * wa[8] + r2.y * wa[9] + r2.z * wa[10] + r2.w * wa[11]
                + r3.x * wa[12] + r3.y * wa[13] + r3.z * wa[14] + r3.w * wa[15];
        se[(size_t)l * N_ED + pos] = make_int2(sk, __float_as_int(e));
    }
}

// fused per-layer conv: 4 nodes per wave-iteration (16-lane group per node),
// static strided schedule. Phase 1 software-pipelined: next chunk's (src,elog)
// 8B load + hs gather issue under current chunk's softmax/phase-2.
// Inactive lanes carry elog=-1e38 sentinel -> exp collapses to 0 naturally.
__global__ void k_layer(const float* __restrict__ h_in,
                        const float* __restrict__ hs, const float* __restrict__ hd,
                        const int* __restrict__ off,
                        const int2* __restrict__ se_l,     // packed (src, elog bits)
                        const float* __restrict__ r16_perm,
                        const float* __restrict__ Wm_l,
                        const float* __restrict__ WeWm_l,
                        const float* __restrict__ a_s_n, const float* __restrict__ a_d_n,
                        float* __restrict__ h_out,
                        float* __restrict__ hs_out, float* __restrict__ hd_out) {
    __shared__ float Wl[4096];
    __shared__ float Ww[1024];
    __shared__ float arow[8][4 * 68 + 4];   // 68-pad: groups land on distinct banks
    int tid = threadIdx.x;
    for (int i = tid; i < 4096; i += 512) Wl[i] = Wm_l[i];
    for (int i = tid; i < 1024; i += 512) Ww[i] = WeWm_l[i];
    __syncthreads();
    int lane = tid & 63, w = tid >> 6;
    int g = lane >> 4, lg = lane & 15;
    float4 as4 = *(const float4*)&a_s_n[lg << 2];
    float4 ad4 = *(const float4*)&a_d_n[lg << 2];
    const int SENT = __float_as_int(-1e38f);
    int Wv = blockIdx.x * 8 + w;
    int NW = gridDim.x * 8;
    for (int nb = Wv * 4; nb < N_RN; nb += NW * 4) {
        int n = nb + g;
        bool nact = n < N_RN;
        int base = 0, end = 0;
        if (nact) { base = off[n]; end = off[n + 1]; }
        float hdn = nact ? hd[n] : 0.f;
        float m = -1e38f, s = 0.f, racc = 0.f;
        float ax = 0.f, ay = 0.f, az = 0.f, aw = 0.f;
        int nch = (end - base + 15) >> 4;
        int nmax = nch;
        nmax = max(nmax, __shfl_xor(nmax, 16, 64));
        nmax = max(nmax, __shfl_xor(nmax, 32, 64));
        // prefetch chunk 0
        int2 v = make_int2(0, SENT);
        if (lg < end - base) v = se_l[base + lg];
        float hsv = hs[v.x];
        for (int c = 0; c < nmax; ++c) {
            int cb = base + (c << 4);
            int rem = end - cb;
            int cnt = rem > 16 ? 16 : (rem > 0 ? rem : 0);
            // issue next chunk's se load (independent of this chunk)
            int2 vn = make_int2(0, SENT);
            int cbn = cb + 16;
            if (lg < end - cbn) vn = se_l[cbn + lg];
            // ---- phase 1 with prefetched v/hsv ----
            float ep = __int_as_float(v.y);
            float lgt = lrelu(hsv + hdn + ep);     // sentinel -> ~ -1e37
            float cm = lgt;
            cm = fmaxf(cm, __shfl_xor(cm, 1, 16));
            cm = fmaxf(cm, __shfl_xor(cm, 2, 16));
            cm = fmaxf(cm, __shfl_xor(cm, 4, 16));
            cm = fmaxf(cm, __shfl_xor(cm, 8, 16));
            float newm = fmaxf(m, cm);
            float scale = (m > -1e37f) ? __expf(m - newm) : 0.f;
            s *= scale; racc *= scale;
            ax *= scale; ay *= scale; az *= scale; aw *= scale;
            m = newm;
            float wvv = __expf(lgt - m);           // inactive -> exp(-huge) = 0
            s += wvv;
            int sk = v.x;
            // issue next chunk's hs gather (vn arrived during softmax above)
            float hsn = hs[vn.x];
            // ---- phase 2: unrolled x4; lane lg accumulates dims 4lg..4lg+3 ----
            const float* hb = h_in;
            int e = 0;
            for (; e + 3 < cnt; e += 4) {
                float w0 = __shfl(wvv, e, 16);
                float w1 = __shfl(wvv, e + 1, 16);
                float w2 = __shfl(wvv, e + 2, 16);
                float w3 = __shfl(wvv, e + 3, 16);
                int   s0 = __shfl(sk, e, 16);
                int   s1 = __shfl(sk, e + 1, 16);
                int   s2 = __shfl(sk, e + 2, 16);
                int   s3 = __shfl(sk, e + 3, 16);
                const float4 h0v = *(const float4*)(hb + (size_t)s0 * 64 + (lg << 2));
                const float4 h1v = *(const float4*)(hb + (size_t)s1 * 64 + (lg << 2));
                const float4 h2v = *(const float4*)(hb + (size_t)s2 * 64 + (lg << 2));
                const float4 h3v = *(const float4*)(hb + (size_t)s3 * 64 + (lg << 2));
                float q0 = r16_perm[(size_t)(cb + e) * 16 + lg];
                float q1 = r16_perm[(size_t)(cb + e + 1) * 16 + lg];
                float q2 = r16_perm[(size_t)(cb + e + 2) * 16 + lg];
                float q3 = r16_perm[(size_t)(cb + e + 3) * 16 + lg];
                ax += w0 * h0v.x + w1 * h1v.x + w2 * h2v.x + w3 * h3v.x;
                ay += w0 * h0v.y + w1 * h1v.y + w2 * h2v.y + w3 * h3v.y;
                az += w0 * h0v.z + w1 * h1v.z + w2 * h2v.z + w3 * h3v.z;
                aw += w0 * h0v.w + w1 * h1v.w + w2 * h2v.w + w3 * h3v.w;
                racc += w0 * q0 + w1 * q1 + w2 * q2 + w3 * q3;
            }
            for (; e < cnt; ++e) {
                float w0 = __shfl(wvv, e, 16);
                int   s0 = __shfl(sk, e, 16);
                const float4 h0v = *(const float4*)(hb + (size_t)s0 * 64 + (lg << 2));
                float q0 = r16_perm[(size_t)(cb + e) * 16 + lg];
                ax += w0 * h0v.x; ay += w0 * h0v.y;
                az += w0 * h0v.z; aw += w0 * h0v.w;
                racc += w0 * q0;
            }
            v = vn; hsv = hsn;
        }
        // softmax denominator (group sum)
        s += __shfl_xor(s, 1, 16);
        s += __shfl_xor(s, 2, 16);
        s += __shfl_xor(s, 4, 16);
        s += __shfl_xor(s, 8, 16);
        float inv = (end > base) ? 1.f / s : 0.f;
        // stage normalized agg row for the group matvec
        float* ar = &arow[w][g * 68];
        *(float4*)&ar[lg << 2] = make_float4(ax * inv, ay * inv, az * inv, aw * inv);
        float mx = 0.f, my = 0.f, mz = 0.f, mw = 0.f;
#pragma unroll
        for (int d4 = 0; d4 < 16; ++d4) {
            float4 a = *(const float4*)&ar[d4 << 2];      // LDS broadcast within group
            const float* wl = &Wl[(d4 << 2) * 64 + (lg << 2)];
            float4 w0 = *(const float4*)&wl[0];
            float4 w1 = *(const float4*)&wl[64];
            float4 w2 = *(const float4*)&wl[128];
            float4 w3 = *(const float4*)&wl[192];
            mx += a.x * w0.x + a.y * w1.x + a.z * w2.x + a.w * w3.x;
            my += a.x * w0.y + a.y * w1.y + a.z * w2.y + a.w * w3.y;
            mz += a.x * w0.z + a.y * w1.z + a.z * w2.z + a.w * w3.z;
            mw += a.x * w0.w + a.y * w1.w + a.z * w2.w + a.w * w3.w;
        }
        float rs = racc * inv;
#pragma unroll
        for (int t = 0; t < 16; ++t) {
            float rt = __shfl(rs, t, 16);
            const float4 wt = *(const float4*)&Ww[t * 64 + (lg << 2)];
            mx += rt * wt.x; my += rt * wt.y; mz += rt * wt.z; mw += rt * wt.w;
        }
        if (nact) {
            const float4 hi4 = *(const float4*)(h_in + (size_t)n * 64 + (lg << 2));
            float4 hv;
            hv.x = lrelu(hi4.x + mx); hv.y = lrelu(hi4.y + my);
            hv.z = lrelu(hi4.z + mz); hv.w = lrelu(hi4.w + mw);
            *(float4*)(h_out + (size_t)n * 64 + (lg << 2)) = hv;
            float x = hv.x * as4.x + hv.y * as4.y + hv.z * as4.z + hv.w * as4.w;
            float y = hv.x * ad4.x + hv.y * ad4.y + hv.z * ad4.z + hv.w * ad4.w;
            x += __shfl_xor(x, 1, 16); x += __shfl_xor(x, 2, 16);
            x += __shfl_xor(x, 4, 16); x += __shfl_xor(x, 8, 16);
            y += __shfl_xor(y, 1, 16); y += __shfl_xor(y, 2, 16);
            y += __shfl_xor(y, 4, 16); y += __shfl_xor(y, 8, 16);
            if (lg == 0) { hs_out[n] = x; hd_out[n] = y; }
        }
    }
}

// block per graph readout (graph_id sorted -> contiguous ranges via binary search)
__global__ void k_readout(const float* __restrict__ h,
                          const float* __restrict__ d_edge,
                          const int* __restrict__ graph_id,
                          const float* __restrict__ i_node,
                          const float* __restrict__ W_i,
                          const float* __restrict__ w_d,
                          const float* __restrict__ b_d,
                          const float* __restrict__ W_mlp,
                          const float* __restrict__ b_mlp,
                          const float* __restrict__ W_out,
                          const float* __restrict__ b_out,
                          float* __restrict__ out) {
    int g = blockIdx.x, j = threadIdx.x;
    int lo = 0, hi = N_RN;
    while (lo < hi) { int mid = (lo + hi) >> 1; if (graph_id[mid] < g) lo = mid + 1; else hi = mid; }
    int start = lo;
    hi = N_RN;
    while (lo < hi) { int mid = (lo + hi) >> 1; if (graph_id[mid] < g + 1) lo = mid + 1; else hi = mid; }
    int end = lo;

    float wd = w_d[0], bd = b_d[0];
    float acc0 = 0.f, acc1 = 0.f, sg = 0.f;
    for (int n = start; n < end; ++n) {
        float hv = h[(size_t)n * 64 + j];
        float de = d_edge[n];
        float gate = 1.f / (1.f + __expf(-(de * wd + bd)));
        acc0 += hv;
        acc1 += gate * hv;
        sg += gate;
    }
    float hij = i_node[g] * W_i[j] + acc1;
    float pooled = acc0 + sg * hij;

    __shared__ float xa[64], xb[64];
    xa[j] = pooled;
    __syncthreads();
#pragma unroll
    for (int layer = 0; layer < 3; ++layer) {
        const float* W = W_mlp + layer * 4096;
        float* srcb = (layer & 1) ? xb : xa;
        float* dstb = (layer & 1) ? xa : xb;
        float acc = b_mlp[layer * 64 + j];
        for (int d = 0; d < 64; ++d) acc += srcb[d] * W[d * 64 + j];
        acc = fmaxf(acc, 0.f);
        __syncthreads();
        dstb[j] = acc;
        __syncthreads();
    }
    float v = xb[j] * W_out[j];
#pragma unroll
    for (int off = 32; off; off >>= 1) v += __shfl_xor(v, off, 64);
    if (j == 0) out[g] = v + b_out[0];
}

extern "C" void kernel_launch(void* const* d_in, const int* in_sizes, int n_in,
                              void* d_out, int out_size, void* d_ws, size_t ws_size,
                              hipStream_t stream) {
    const float* r_node  = (const float*)d_in[0];
    const float* i_node  = (const float*)d_in[1];
    const float* r_edge  = (const float*)d_in[2];
    const float* d_edge  = (const float*)d_in[3];
    const int*   r2r_src = (const int*)d_in[4];
    const int*   r2r_dst = (const int*)d_in[5];
    const int*   graph_id= (const int*)d_in[6];
    const float* W_r     = (const float*)d_in[7];
    const float* W_i     = (const float*)d_in[8];
    const float* W_e     = (const float*)d_in[9];
    const float* Wm      = (const float*)d_in[10];
    const float* a_s     = (const float*)d_in[11];
    const float* a_d     = (const float*)d_in[12];
    const float* a_e     = (const float*)d_in[13];
    const float* w_d     = (const float*)d_in[14];
    const float* b_d     = (const float*)d_in[15];
    const float* W_mlp   = (const float*)d_in[16];
    const float* b_mlp   = (const float*)d_in[17];
    const float* W_out   = (const float*)d_in[18];
    const float* b_out   = (const float*)d_in[19];
    float* out = (float*)d_out;

    float* ws = (float*)d_ws;
    float* h0   = ws;                                  // N*64
    float* h1   = h0 + (size_t)N_RN * 64;              // N*64
    float* hs0  = h1 + (size_t)N_RN * 64;              // N
    float* hd0  = hs0 + N_RN;                          // N
    float* hs1  = hd0 + N_RN;                          // N
    float* hd1  = hs1 + N_RN;                          // N
    float* WeWm = hd1 + N_RN;                          // 4*16*64
    float* wasb = WeWm + 4096;                         // 4*16
    int*   deg  = (int*)(wasb + 64);                   // N
    int*   offs = deg + N_RN;                          // N+1
    int*   cur  = offs + N_RN + 1;                     // N
    int*   bsum = cur + N_RN;                          // 512
    int*   eperm= bsum + 512;                          // E
    int2*  se   = (int2*)(eperm + N_ED);               // 4*E int2
    float* r16_perm = (float*)(se + (size_t)4 * N_ED); // 16*E

    // CSR build + permute FIRST (their write burst drains before the layers)
    k_wewm<<<17, 256, 0, stream>>>(W_e, Wm, a_e, WeWm, wasb);
    hipMemsetAsync(deg, 0, N_RN * sizeof(int), stream);
    k_hist<<<(N_ED + 255) / 256, 256, 0, stream>>>(r2r_dst, deg);
    k_scan_a<<<SCAN_NB, SCAN_CH, 0, stream>>>(deg, bsum);
    k_scan_b<<<1, 512, 0, stream>>>(bsum);
    k_scan_c<<<SCAN_NB, SCAN_CH, 0, stream>>>(deg, bsum, offs, cur);
    k_scatter_idx<<<(N_ED + 255) / 256, 256, 0, stream>>>(r2r_dst, cur, eperm);
    k_permute<<<(N_ED + 255) / 256, 256, 0, stream>>>(eperm, r2r_src, r_edge, wasb,
                                                      se, r16_perm);

    // embed last: h0/hs0/hd0 are the freshest data when layer 0 starts
    k_embed_h<<<2048, 256, 0, stream>>>(r_node, W_r, a_s, a_d, h0, hs0, hd0);

    float* hin = h0;  float* hout = h1;
    float* hsi = hs0; float* hdi = hd0;
    float* hso = hs1; float* hdo = hd1;
    for (int l = 0; l < 4; ++l) {
        int ln = (l + 1) & 3;
        k_layer<<<1024, 512, 0, stream>>>(hin, hsi, hdi, offs,
                                          se + (size_t)l * N_ED, r16_perm,
                                          Wm + l * 4096, WeWm + l * 1024,
                                          a_s + ln * 64, a_d + ln * 64,
                                          hout, hso, hdo);
        float* t;
        t = hin; hin = hout; hout = t;
        t = hsi; hsi = hso; hso = t;
        t = hdi; hdi = hdo; hdo = t;
    }

    k_readout<<<N_G, 64, 0, stream>>>(hin, d_edge, graph_id, i_node, W_i, w_d, b_d,
                                      W_mlp, b_mlp, W_out, b_out, out);
}

// Round 8
// 711.902 us; speedup vs baseline: 2.3522x; 1.0912x over previous
//
#include <hip/hip_runtime.h>
#include <hip/hip_fp16.h>
#include <math.h>

#define N_RN 100000
#define N_ED 1200000
#define N_G  4096
#define SCAN_CH 256
#define SCAN_NB ((N_RN + SCAN_CH - 1) / SCAN_CH)   // 391

__device__ __forceinline__ float lrelu(float x) { return x > 0.f ? x : 0.1f * x; }

// h = r_node @ W_r (wave/node, lane=col); fused hs/hd layer0; writes fp16 mirror
__global__ void k_embed_h(const float* __restrict__ r_node,
                          const float* __restrict__ W_r,
                          const float* __restrict__ a_s0,
                          const float* __restrict__ a_d0,
                          float* __restrict__ h,
                          __half* __restrict__ h16,
                          float* __restrict__ hs, float* __restrict__ hd) {
    __shared__ float Wl[64 * 64];
    __shared__ float arow[4][64];
    int tid = threadIdx.x;
    for (int i = tid; i < 4096; i += 256) Wl[i] = W_r[i];
    __syncthreads();
    int lane = tid & 63, w = tid >> 6;
    float asj = a_s0[lane], adj = a_d0[lane];
    int wid = blockIdx.x * 4 + w;
    int nw = gridDim.x * 4;
    for (int n = wid; n < N_RN; n += nw) {
        arow[w][lane] = r_node[(size_t)n * 64 + lane];
        float acc = 0.f;
#pragma unroll
        for (int d4 = 0; d4 < 16; ++d4) {
            float4 a = *(const float4*)&arow[w][d4 * 4];
            int d = d4 * 4;
            acc += a.x * Wl[(d + 0) * 64 + lane];
            acc += a.y * Wl[(d + 1) * 64 + lane];
            acc += a.z * Wl[(d + 2) * 64 + lane];
            acc += a.w * Wl[(d + 3) * 64 + lane];
        }
        h[(size_t)n * 64 + lane] = acc;
        h16[(size_t)n * 64 + lane] = __float2half(acc);
        float x = acc * asj, y = acc * adj;
#pragma unroll
        for (int off = 32; off; off >>= 1) {
            x += __shfl_xor(x, off, 64);
            y += __shfl_xor(y, off, 64);
        }
        if (lane == 0) { hs[n] = x; hd[n] = y; }
    }
}

// WeWm[l] = W_e @ Wm[l]; was_all[l][t] = W_e[t,:] . a_e[l]
__global__ void k_wewm(const float* __restrict__ W_e,
                       const float* __restrict__ Wm,
                       const float* __restrict__ a_e,
                       float* __restrict__ WeWm,
                       float* __restrict__ was_all) {
    int idx = blockIdx.x * blockDim.x + threadIdx.x;   // 17*256
    if (idx < 4096) {
        int l = idx >> 10, rem = idx & 1023;
        int t = rem >> 6, j = rem & 63;
        float acc = 0.f;
        for (int d = 0; d < 64; ++d)
            acc += W_e[t * 64 + d] * Wm[l * 4096 + d * 64 + j];
        WeWm[idx] = acc;
    } else {
        int r = idx - 4096;
        if (r < 64) {
            int l = r >> 4, t = r & 15;
            float acc = 0.f;
            for (int j = 0; j < 64; ++j)
                acc += W_e[t * 64 + j] * a_e[l * 64 + j];
            was_all[r] = acc;
        }
    }
}

// ---- CSR build ----
// histogram + per-edge rank (the atomic's return value), coalesced rank write
__global__ void k_hist(const int* __restrict__ dst, int* __restrict__ deg,
                       int* __restrict__ rank) {
    int k = blockIdx.x * blockDim.x + threadIdx.x;
    if (k < N_ED) rank[k] = atomicAdd(deg + dst[k], 1);
}

__global__ void k_scan_a(const int* __restrict__ deg, int* __restrict__ bsum) {
    __shared__ int lds[SCAN_CH];
    int b = blockIdx.x, t = threadIdx.x;
    int i = b * SCAN_CH + t;
    int v = (i < N_RN) ? deg[i] : 0;
    lds[t] = v;
    __syncthreads();
    for (int d = 128; d; d >>= 1) {
        if (t < d) lds[t] += lds[t + d];
        __syncthreads();
    }
    if (t == 0) bsum[b] = lds[0];
}

__global__ void k_scan_b(int* __restrict__ bsum) {
    __shared__ int lds[512];
    int t = threadIdx.x;
    int v = (t < SCAN_NB) ? bsum[t] : 0;
    lds[t] = v;
    __syncthreads();
    for (int d = 1; d < 512; d <<= 1) {
        int u = (t >= d) ? lds[t - d] : 0;
        __syncthreads();
        lds[t] += u;
        __syncthreads();
    }
    if (t < SCAN_NB) bsum[t] = lds[t] - v;  // exclusive
}

__global__ void k_scan_c(const int* __restrict__ deg, const int* __restrict__ bsum,
                         int* __restrict__ off) {
    __shared__ int lds[SCAN_CH];
    int b = blockIdx.x, t = threadIdx.x;
    int i = b * SCAN_CH + t;
    int v = (i < N_RN) ? deg[i] : 0;
    lds[t] = v;
    __syncthreads();
    for (int d = 1; d < SCAN_CH; d <<= 1) {
        int u = (t >= d) ? lds[t - d] : 0;
        __syncthreads();
        lds[t] += u;
        __syncthreads();
    }
    if (i < N_RN) {
        off[i + 1] = bsum[b] + lds[t];
        if (i == 0) off[0] = 0;
    }
}

// atomic-free inverted scatter: pos = off[dst] + rank; nt store; grid-stride MLP
__global__ void k_scatter_idx(const int* __restrict__ dst,
                              const int* __restrict__ rank,
                              const int* __restrict__ off,
                              int* __restrict__ eperm) {
    int tid = blockIdx.x * blockDim.x + threadIdx.x;
    int nt = gridDim.x * blockDim.x;
    for (int k = tid; k < N_ED; k += nt) {
        int pos = off[dst[k]] + rank[k];
        __builtin_nontemporal_store(k, eperm + pos);
    }
}

// coalesced-write permute: packed (src, elog) int2 planes + fp16 r16 rows
__global__ void k_permute(const int* __restrict__ eperm,
                          const int* __restrict__ src,
                          const float* __restrict__ r_edge,
                          const float* __restrict__ was_all,  // 4x16
                          int2* __restrict__ se,
                          __half* __restrict__ r16h) {
    int pos = blockIdx.x * blockDim.x + threadIdx.x;
    if (pos >= N_ED) return;
    int k = eperm[pos];
    int sk = src[k];
    const float4* row = (const float4*)(r_edge + (size_t)k * 16);
    float4 r0 = row[0], r1 = row[1], r2 = row[2], r3 = row[3];
    __half2 p0 = __floats2half2_rn(r0.x, r0.y), p1 = __floats2half2_rn(r0.z, r0.w);
    __half2 p2 = __floats2half2_rn(r1.x, r1.y), p3 = __floats2half2_rn(r1.z, r1.w);
    __half2 p4 = __floats2half2_rn(r2.x, r2.y), p5 = __floats2half2_rn(r2.z, r2.w);
    __half2 p6 = __floats2half2_rn(r3.x, r3.y), p7 = __floats2half2_rn(r3.z, r3.w);
    uint4* o = (uint4*)(r16h + (size_t)pos * 16);
    o[0] = make_uint4(*(unsigned*)&p0, *(unsigned*)&p1, *(unsigned*)&p2, *(unsigned*)&p3);
    o[1] = make_uint4(*(unsigned*)&p4, *(unsigned*)&p5, *(unsigned*)&p6, *(unsigned*)&p7);
#pragma unroll
    for (int l = 0; l < 4; ++l) {
        const float* wa = was_all + l * 16;   // uniform -> scalar loads
        float e = r0.x * wa[0] + r0.y * wa[1] + r0.z * wa[2] + r0.w * wa[3]
                + r1.x * wa[4] + r1.y * wa[5] + r1.z * wa[6] + r1.w * wa[7]
                + r2.x * wa[8] + r2.y * wa[9] + r2.z * wa[10] + r2.w * wa[11]
                + r3.x * wa[12] + r3.y * wa[13] + r3.z * wa[14] + r3.w * wa[15];
        se[(size_t)l * N_ED + pos] = make_int2(sk, __float_as_int(e));
    }
}

// fused per-layer conv: 4 nodes/wave (16-lane group per node), strided schedule.
// Phase 1 pipelined (se prefetch + hs gather). Phase 2 gathers fp16 h rows and
// fp16 r16 stream (half the bytes of R7). Epilogue writes f32 + fp16 h.
__global__ void k_layer(const float* __restrict__ h_in,
                        const __half* __restrict__ h16_in,
                        const float* __restrict__ hs, const float* __restrict__ hd,
                        const int* __restrict__ off,
                        const int2* __restrict__ se_l,
                        const __half* __restrict__ r16h,
                        const float* __restrict__ Wm_l,
                        const float* __restrict__ WeWm_l,
                        const float* __restrict__ a_s_n, const float* __restrict__ a_d_n,
                        float* __restrict__ h_out,
                        __half* __restrict__ h16_out,
                        float* __restrict__ hs_out, float* __restrict__ hd_out) {
    __shared__ float Wl[4096];
    __shared__ float Ww[1024];
    __shared__ float arow[8][4 * 68 + 4];
    int tid = threadIdx.x;
    for (int i = tid; i < 4096; i += 512) Wl[i] = Wm_l[i];
    for (int i = tid; i < 1024; i += 512) Ww[i] = WeWm_l[i];
    __syncthreads();
    int lane = tid & 63, w = tid >> 6;
    int g = lane >> 4, lg = lane & 15;
    float4 as4 = *(const float4*)&a_s_n[lg << 2];
    float4 ad4 = *(const float4*)&a_d_n[lg << 2];
    const int SENT = __float_as_int(-1e38f);
    int Wv = blockIdx.x * 8 + w;
    int NW = gridDim.x * 8;
    for (int nb = Wv * 4; nb < N_RN; nb += NW * 4) {
        int n = nb + g;
        bool nact = n < N_RN;
        int base = 0, end = 0;
        if (nact) { base = off[n]; end = off[n + 1]; }
        float hdn = nact ? hd[n] : 0.f;
        float m = -1e38f, s = 0.f, racc = 0.f;
        float ax = 0.f, ay = 0.f, az = 0.f, aw = 0.f;
        int nch = (end - base + 15) >> 4;
        int nmax = nch;
        nmax = max(nmax, __shfl_xor(nmax, 16, 64));
        nmax = max(nmax, __shfl_xor(nmax, 32, 64));
        // prefetch chunk 0
        int2 v = make_int2(0, SENT);
        if (lg < end - base) v = se_l[base + lg];
        float hsv = hs[v.x];
        for (int c = 0; c < nmax; ++c) {
            int cb = base + (c << 4);
            int rem = end - cb;
            int cnt = rem > 16 ? 16 : (rem > 0 ? rem : 0);
            // issue next chunk's se load
            int2 vn = make_int2(0, SENT);
            int cbn = cb + 16;
            if (lg < end - cbn) vn = se_l[cbn + lg];
            // ---- phase 1 with prefetched v/hsv ----
            float ep = __int_as_float(v.y);
            float lgt = lrelu(hsv + hdn + ep);
            float cm = lgt;
            cm = fmaxf(cm, __shfl_xor(cm, 1, 16));
            cm = fmaxf(cm, __shfl_xor(cm, 2, 16));
            cm = fmaxf(cm, __shfl_xor(cm, 4, 16));
            cm = fmaxf(cm, __shfl_xor(cm, 8, 16));
            float newm = fmaxf(m, cm);
            float scale = (m > -1e37f) ? __expf(m - newm) : 0.f;
            s *= scale; racc *= scale;
            ax *= scale; ay *= scale; az *= scale; aw *= scale;
            m = newm;
            float wvv = __expf(lgt - m);
            s += wvv;
            int sk = v.x;
            float hsn = hs[vn.x];
            // ---- phase 2: x4 unroll, fp16 gathers ----
            int e = 0;
            for (; e + 3 < cnt; e += 4) {
                float w0 = __shfl(wvv, e, 16);
                float w1 = __shfl(wvv, e + 1, 16);
                float w2 = __shfl(wvv, e + 2, 16);
                float w3 = __shfl(wvv, e + 3, 16);
                int   s0 = __shfl(sk, e, 16);
                int   s1 = __shfl(sk, e + 1, 16);
                int   s2 = __shfl(sk, e + 2, 16);
                int   s3 = __shfl(sk, e + 3, 16);
                uint2 hp0 = *(const uint2*)(h16_in + (size_t)s0 * 64 + (lg << 2));
                uint2 hp1 = *(const uint2*)(h16_in + (size_t)s1 * 64 + (lg << 2));
                uint2 hp2 = *(const uint2*)(h16_in + (size_t)s2 * 64 + (lg << 2));
                uint2 hp3 = *(const uint2*)(h16_in + (size_t)s3 * 64 + (lg << 2));
                float q0 = __half2float(r16h[(size_t)(cb + e) * 16 + lg]);
                float q1 = __half2float(r16h[(size_t)(cb + e + 1) * 16 + lg]);
                float q2 = __half2float(r16h[(size_t)(cb + e + 2) * 16 + lg]);
                float q3 = __half2float(r16h[(size_t)(cb + e + 3) * 16 + lg]);
                float2 a0 = __half22float2(*(__half2*)&hp0.x);
                float2 b0 = __half22float2(*(__half2*)&hp0.y);
                float2 a1 = __half22float2(*(__half2*)&hp1.x);
                float2 b1 = __half22float2(*(__half2*)&hp1.y);
                float2 a2 = __half22float2(*(__half2*)&hp2.x);
                float2 b2 = __half22float2(*(__half2*)&hp2.y);
                float2 a3 = __half22float2(*(__half2*)&hp3.x);
                float2 b3 = __half22float2(*(__half2*)&hp3.y);
                ax += w0 * a0.x + w1 * a1.x + w2 * a2.x + w3 * a3.x;
                ay += w0 * a0.y + w1 * a1.y + w2 * a2.y + w3 * a3.y;
                az += w0 * b0.x + w1 * b1.x + w2 * b2.x + w3 * b3.x;
                aw += w0 * b0.y + w1 * b1.y + w2 * b2.y + w3 * b3.y;
                racc += w0 * q0 + w1 * q1 + w2 * q2 + w3 * q3;
            }
            for (; e < cnt; ++e) {
                float w0 = __shfl(wvv, e, 16);
                int   s0 = __shfl(sk, e, 16);
                uint2 hp0 = *(const uint2*)(h16_in + (size_t)s0 * 64 + (lg << 2));
                float q0 = __half2float(r16h[(size_t)(cb + e) * 16 + lg]);
                float2 a0 = __half22float2(*(__half2*)&hp0.x);
                float2 b0 = __half22float2(*(__half2*)&hp0.y);
                ax += w0 * a0.x; ay += w0 * a0.y;
                az += w0 * b0.x; aw += w0 * b0.y;
                racc += w0 * q0;
            }
            v = vn; hsv = hsn;
        }
        // softmax denominator (group sum)
        s += __shfl_xor(s, 1, 16);
        s += __shfl_xor(s, 2, 16);
        s += __shfl_xor(s, 4, 16);
        s += __shfl_xor(s, 8, 16);
        float inv = (end > base) ? 1.f / s : 0.f;
        float* ar = &arow[w][g * 68];
        *(float4*)&ar[lg << 2] = make_float4(ax * inv, ay * inv, az * inv, aw * inv);
        float mx = 0.f, my = 0.f, mz = 0.f, mw = 0.f;
#pragma unroll
        for (int d4 = 0; d4 < 16; ++d4) {
            float4 a = *(const float4*)&ar[d4 << 2];
            const float* wl = &Wl[(d4 << 2) * 64 + (lg << 2)];
            float4 w0 = *(const float4*)&wl[0];
            float4 w1 = *(const float4*)&wl[64];
            float4 w2 = *(const float4*)&wl[128];
            float4 w3 = *(const float4*)&wl[192];
            mx += a.x * w0.x + a.y * w1.x + a.z * w2.x + a.w * w3.x;
            my += a.x * w0.y + a.y * w1.y + a.z * w2.y + a.w * w3.y;
            mz += a.x * w0.z + a.y * w1.z + a.z * w2.z + a.w * w3.z;
            mw += a.x * w0.w + a.y * w1.w + a.z * w2.w + a.w * w3.w;
        }
        float rs = racc * inv;
#pragma unroll
        for (int t = 0; t < 16; ++t) {
            float rt = __shfl(rs, t, 16);
            const float4 wt = *(const float4*)&Ww[t * 64 + (lg << 2)];
            mx += rt * wt.x; my += rt * wt.y; mz += rt * wt.z; mw += rt * wt.w;
        }
        if (nact) {
            const float4 hi4 = *(const float4*)(h_in + (size_t)n * 64 + (lg << 2));
            float4 hv;
            hv.x = lrelu(hi4.x + mx); hv.y = lrelu(hi4.y + my);
            hv.z = lrelu(hi4.z + mz); hv.w = lrelu(hi4.w + mw);
            *(float4*)(h_out + (size_t)n * 64 + (lg << 2)) = hv;
            __half2 p0 = __floats2half2_rn(hv.x, hv.y);
            __half2 p1 = __floats2half2_rn(hv.z, hv.w);
            *(uint2*)(h16_out + (size_t)n * 64 + (lg << 2)) =
                make_uint2(*(unsigned*)&p0, *(unsigned*)&p1);
            float x = hv.x * as4.x + hv.y * as4.y + hv.z * as4.z + hv.w * as4.w;
            float y = hv.x * ad4.x + hv.y * ad4.y + hv.z * ad4.z + hv.w * ad4.w;
            x += __shfl_xor(x, 1, 16); x += __shfl_xor(x, 2, 16);
            x += __shfl_xor(x, 4, 16); x += __shfl_xor(x, 8, 16);
            y += __shfl_xor(y, 1, 16); y += __shfl_xor(y, 2, 16);
            y += __shfl_xor(y, 4, 16); y += __shfl_xor(y, 8, 16);
            if (lg == 0) { hs_out[n] = x; hd_out[n] = y; }
        }
    }
}

// block per graph readout (graph_id sorted -> contiguous ranges via binary search)
__global__ void k_readout(const float* __restrict__ h,
                          const float* __restrict__ d_edge,
                          const int* __restrict__ graph_id,
                          const float* __restrict__ i_node,
                          const float* __restrict__ W_i,
                          const float* __restrict__ w_d,
                          const float* __restrict__ b_d,
                          const float* __restrict__ W_mlp,
                          const float* __restrict__ b_mlp,
                          const float* __restrict__ W_out,
                          const float* __restrict__ b_out,
                          float* __restrict__ out) {
    int g = blockIdx.x, j = threadIdx.x;
    int lo = 0, hi = N_RN;
    while (lo < hi) { int mid = (lo + hi) >> 1; if (graph_id[mid] < g) lo = mid + 1; else hi = mid; }
    int start = lo;
    hi = N_RN;
    while (lo < hi) { int mid = (lo + hi) >> 1; if (graph_id[mid] < g + 1) lo = mid + 1; else hi = mid; }
    int end = lo;

    float wd = w_d[0], bd = b_d[0];
    float acc0 = 0.f, acc1 = 0.f, sg = 0.f;
    for (int n = start; n < end; ++n) {
        float hv = h[(size_t)n * 64 + j];
        float de = d_edge[n];
        float gate = 1.f / (1.f + __expf(-(de * wd + bd)));
        acc0 += hv;
        acc1 += gate * hv;
        sg += gate;
    }
    float hij = i_node[g] * W_i[j] + acc1;
    float pooled = acc0 + sg * hij;

    __shared__ float xa[64], xb[64];
    xa[j] = pooled;
    __syncthreads();
#pragma unroll
    for (int layer = 0; layer < 3; ++layer) {
        const float* W = W_mlp + layer * 4096;
        float* srcb = (layer & 1) ? xb : xa;
        float* dstb = (layer & 1) ? xa : xb;
        float acc = b_mlp[layer * 64 + j];
        for (int d = 0; d < 64; ++d) acc += srcb[d] * W[d * 64 + j];
        acc = fmaxf(acc, 0.f);
        __syncthreads();
        dstb[j] = acc;
        __syncthreads();
    }
    float v = xb[j] * W_out[j];
#pragma unroll
    for (int off = 32; off; off >>= 1) v += __shfl_xor(v, off, 64);
    if (j == 0) out[g] = v + b_out[0];
}

extern "C" void kernel_launch(void* const* d_in, const int* in_sizes, int n_in,
                              void* d_out, int out_size, void* d_ws, size_t ws_size,
                              hipStream_t stream) {
    const float* r_node  = (const float*)d_in[0];
    const float* i_node  = (const float*)d_in[1];
    const float* r_edge  = (const float*)d_in[2];
    const float* d_edge  = (const float*)d_in[3];
    const int*   r2r_src = (const int*)d_in[4];
    const int*   r2r_dst = (const int*)d_in[5];
    const int*   graph_id= (const int*)d_in[6];
    const float* W_r     = (const float*)d_in[7];
    const float* W_i     = (const float*)d_in[8];
    const float* W_e     = (const float*)d_in[9];
    const float* Wm      = (const float*)d_in[10];
    const float* a_s     = (const float*)d_in[11];
    const float* a_d     = (const float*)d_in[12];
    const float* a_e     = (const float*)d_in[13];
    const float* w_d     = (const float*)d_in[14];
    const float* b_d     = (const float*)d_in[15];
    const float* W_mlp   = (const float*)d_in[16];
    const float* b_mlp   = (const float*)d_in[17];
    const float* W_out   = (const float*)d_in[18];
    const float* b_out   = (const float*)d_in[19];
    float* out = (float*)d_out;

    float* ws = (float*)d_ws;
    float* h0   = ws;                                  // N*64
    float* h1   = h0 + (size_t)N_RN * 64;              // N*64
    float* hs0  = h1 + (size_t)N_RN * 64;              // N
    float* hd0  = hs0 + N_RN;                          // N
    float* hs1  = hd0 + N_RN;                          // N
    float* hd1  = hs1 + N_RN;                          // N
    float* WeWm = hd1 + N_RN;                          // 4*16*64
    float* wasb = WeWm + 4096;                         // 4*16
    int*   deg  = (int*)(wasb + 64);                   // N
    int*   offs = deg + N_RN;                          // N+1
    int*   rank = offs + N_RN + 1;                     // E
    int*   bsum = rank + N_ED;                         // 512
    int*   eperm= bsum + 512;                          // E
    int2*  se   = (int2*)(eperm + N_ED);               // 4*E int2
    __half* r16h = (__half*)(se + (size_t)4 * N_ED);   // 16*E halfs
    __half* h16a = r16h + (size_t)N_ED * 16;           // N*64 halfs
    __half* h16b = h16a + (size_t)N_RN * 64;           // N*64 halfs

    // CSR build + permute first
    k_wewm<<<17, 256, 0, stream>>>(W_e, Wm, a_e, WeWm, wasb);
    hipMemsetAsync(deg, 0, N_RN * sizeof(int), stream);
    k_hist<<<(N_ED + 255) / 256, 256, 0, stream>>>(r2r_dst, deg, rank);
    k_scan_a<<<SCAN_NB, SCAN_CH, 0, stream>>>(deg, bsum);
    k_scan_b<<<1, 512, 0, stream>>>(bsum);
    k_scan_c<<<SCAN_NB, SCAN_CH, 0, stream>>>(deg, bsum, offs);
    k_scatter_idx<<<1172, 256, 0, stream>>>(r2r_dst, rank, offs, eperm);
    k_permute<<<(N_ED + 255) / 256, 256, 0, stream>>>(eperm, r2r_src, r_edge, wasb,
                                                      se, r16h);

    // embed last: h0/h16a/hs0/hd0 freshest when layer 0 starts
    k_embed_h<<<2048, 256, 0, stream>>>(r_node, W_r, a_s, a_d, h0, h16a, hs0, hd0);

    float* hin = h0;  float* hout = h1;
    __half* h16i = h16a; __half* h16o = h16b;
    float* hsi = hs0; float* hdi = hd0;
    float* hso = hs1; float* hdo = hd1;
    for (int l = 0; l < 4; ++l) {
        int ln = (l + 1) & 3;
        k_layer<<<1024, 512, 0, stream>>>(hin, h16i, hsi, hdi, offs,
                                          se + (size_t)l * N_ED, r16h,
                                          Wm + l * 4096, WeWm + l * 1024,
                                          a_s + ln * 64, a_d + ln * 64,
                                          hout, h16o, hso, hdo);
        float* t;
        t = hin; hin = hout; hout = t;
        t = hsi; hsi = hso; hso = t;
        t = hdi; hdi = hdo; hdo = t;
        __half* th = h16i; h16i = h16o; h16o = th;
    }

    k_readout<<<N_G, 64, 0, stream>>>(hin, d_edge, graph_id, i_node, W_i, w_d, b_d,
                                      W_mlp, b_mlp, W_out, b_out, out);
}